// Round 1
// 562.623 us; speedup vs baseline: 1.1934x; 1.1934x over previous
//
#include <hip/hip_runtime.h>
#include <hip/hip_fp16.h>
#include <cfloat>

#define B_    1024
#define T_    4
#define DIN   768
#define KD    3072      // T_*DIN, contracted dim of encoder
#define DSAE  8192
#define TOPK  32

static constexpr size_t XHAT_OFF = 1;
static constexpr size_t Z_OFF    = 1 + (size_t)B_ * T_ * DIN;   // 3145729

typedef __attribute__((ext_vector_type(8))) short    frag;    // 8 bf16 = 4 VGPRs (legacy path)
typedef __attribute__((ext_vector_type(8))) _Float16 hfrag;   // 8 fp16 = 4 VGPRs
typedef __attribute__((ext_vector_type(4))) float    f32x4;   // MFMA C/D

__device__ __forceinline__ unsigned pack2(float a, float b) {
    return (__builtin_bit_cast(unsigned, a) >> 16) | (__builtin_bit_cast(unsigned, b) & 0xFFFF0000u);
}
__device__ __forceinline__ float hi_part(float a) {
    return __builtin_bit_cast(float, __builtin_bit_cast(unsigned, a) & 0xFFFF0000u);
}

// ---------------------------------------------------------------- K0
__global__ void zero_acc(double* acc) { if (threadIdx.x == 0) *acc = 0.0; }

// ---------------------------------------------------------------- FAST PATH: convert kernels
// Xh[row][k] = fp16(x[row][k])   (1024 x 3072)
__global__ __launch_bounds__(256) void convert_x(const float* __restrict__ x, ushort* __restrict__ Xh)
{
    const int row = blockIdx.y;
    const int col = blockIdx.x * 1024 + threadIdx.x * 4;
    const float4 f = *(const float4*)(x + (size_t)row * KD + col);
    ushort4 h;
    h.x = __half_as_ushort(__float2half(f.x));
    h.y = __half_as_ushort(__float2half(f.y));
    h.z = __half_as_ushort(__float2half(f.z));
    h.w = __half_as_ushort(__float2half(f.w));
    *(ushort4*)(Xh + (size_t)row * KD + col) = h;
}

// Wt[n][0..3071]    = fp16(W[k][n])                 (transposed hi)
// Wt[n][3072..6143] = fp16((W[k][n]-hi)*2048)       (transposed scaled residual)
__global__ __launch_bounds__(256) void convert_wT(const float* __restrict__ W, ushort* __restrict__ Wt)
{
    __shared__ float t[64][33];
    const int tx = threadIdx.x & 31, ty = threadIdx.x >> 5;
    const int n0 = blockIdx.x * 32, k0 = blockIdx.y * 64;
    #pragma unroll
    for (int j = 0; j < 8; j++)
        t[ty + j * 8][tx] = W[(size_t)(k0 + ty + j * 8) * DSAE + n0 + tx];
    __syncthreads();
    #pragma unroll
    for (int j = 0; j < 4; j++) {
        const int nl = ty + j * 8;
        const float a = t[tx * 2][nl], b = t[tx * 2 + 1][nl];
        const __half ha = __float2half(a), hb = __float2half(b);
        const float ra = (a - __half2float(ha)) * 2048.0f;
        const float rb = (b - __half2float(hb)) * 2048.0f;
        const ushort2 hv = make_ushort2(__half_as_ushort(ha), __half_as_ushort(hb));
        const ushort2 lv = make_ushort2(__half_as_ushort(__float2half(ra)),
                                        __half_as_ushort(__float2half(rb)));
        ushort* dst = Wt + (size_t)(n0 + nl) * (2 * KD) + k0 + tx * 2;
        *(ushort2*)dst        = hv;
        *(ushort2*)(dst + KD) = lv;
    }
}

// ---------------------------------------------------------------- FAST PATH: fp16 2-product MFMA GEMM
// pre = Xh*Wh + 2^-11 * (Xh*Wl')   ; m97-style 128x128 tile, BK=32, global_load_lds staging.
__device__ __forceinline__ void gload16(const ushort* g, ushort* l)
{
    __builtin_amdgcn_global_load_lds((const __attribute__((address_space(1))) void*)g,
                                     (__attribute__((address_space(3))) void*)l, 16, 0, 0);
}

__global__ __launch_bounds__(256, 2) void encode_gemm(const ushort* __restrict__ Xh,
                                                      const ushort* __restrict__ Wt,
                                                      const float* __restrict__ benc,
                                                      float* __restrict__ pre)
{
    __shared__ ushort As [128 * 32];   // [m][k] 8 KB
    __shared__ ushort Bhs[128 * 32];   // [n][k] hi
    __shared__ ushort Bls[128 * 32];   // [n][k] lo'

    const int tid  = threadIdx.x;
    const int n0   = blockIdx.x * 128, m0 = blockIdx.y * 128;
    const int lane = tid & 63, wv = tid >> 6;
    const int wrow = (wv >> 1) * 64, wcol = (wv & 1) * 64;
    const int lm = lane & 15, q = lane >> 4;

    f32x4 acc[4][4], acc2[4][4];
    #pragma unroll
    for (int i = 0; i < 4; i++)
        #pragma unroll
        for (int j = 0; j < 4; j++) { acc[i][j] = (f32x4){0.f,0.f,0.f,0.f}; acc2[i][j] = (f32x4){0.f,0.f,0.f,0.f}; }

    // staging: per wave 1 KB/call = 16 rows x 64 B; lane l -> row l>>2, 16B-chunk l&3
    const int srow = lane >> 2, scol = (lane & 3) * 8;
    const ushort* pa0 = Xh + (size_t)(m0 + wv * 16 + srow) * KD + scol;
    const ushort* pa1 = pa0 + (size_t)64 * KD;
    const ushort* pb0 = Wt + (size_t)(n0 + wv * 16 + srow) * (2 * KD) + scol;
    const ushort* pb1 = pb0 + (size_t)64 * (2 * KD);
    ushort* da0 = &As [wv * 512]; ushort* da1 = &As [2048 + wv * 512];
    ushort* dh0 = &Bhs[wv * 512]; ushort* dh1 = &Bhs[2048 + wv * 512];
    ushort* dl0 = &Bls[wv * 512]; ushort* dl1 = &Bls[2048 + wv * 512];

    for (int k0 = 0; k0 < KD; k0 += 32) {
        gload16(pa0 + k0,      da0);
        gload16(pa1 + k0,      da1);
        gload16(pb0 + k0,      dh0);
        gload16(pb1 + k0,      dh1);
        gload16(pb0 + KD + k0, dl0);
        gload16(pb1 + KD + k0, dl1);
        __syncthreads();    // compiler emits vmcnt(0) drain before barrier

        hfrag af[4], bh[4], bl[4];
        #pragma unroll
        for (int t4 = 0; t4 < 4; t4++) {
            af[t4] = *(const hfrag*)&As [(wrow + t4 * 16 + lm) * 32 + q * 8];
            bh[t4] = *(const hfrag*)&Bhs[(wcol + t4 * 16 + lm) * 32 + q * 8];
            bl[t4] = *(const hfrag*)&Bls[(wcol + t4 * 16 + lm) * 32 + q * 8];
        }
        #pragma unroll
        for (int mt = 0; mt < 4; mt++)
            #pragma unroll
            for (int nt = 0; nt < 4; nt++) {
                acc [mt][nt] = __builtin_amdgcn_mfma_f32_16x16x32_f16(af[mt], bh[nt], acc [mt][nt], 0, 0, 0);
                acc2[mt][nt] = __builtin_amdgcn_mfma_f32_16x16x32_f16(af[mt], bl[nt], acc2[mt][nt], 0, 0, 0);
            }
        __syncthreads();
    }

    // epilogue: C/D layout col=lane&15, row=q*4+reg  (verified mapping from previous kernel)
    #pragma unroll
    for (int mt = 0; mt < 4; mt++)
        #pragma unroll
        for (int nt = 0; nt < 4; nt++) {
            const int col = n0 + wcol + nt * 16 + lm;
            const float bv = benc[col];
            #pragma unroll
            for (int r = 0; r < 4; r++) {
                const int row = m0 + wrow + mt * 16 + q * 4 + r;
                pre[(size_t)row * DSAE + col] = acc[mt][nt][r] + 4.8828125e-4f * acc2[mt][nt][r] + bv;
            }
        }
}

// ---------------------------------------------------------------- FALLBACK: bf16x2-split MFMA GEMM (unchanged)
#define PK 40
__global__ __launch_bounds__(256, 2) void encode_mfma(const float* __restrict__ x,
                                                      const float* __restrict__ W,
                                                      const float* __restrict__ benc,
                                                      float* __restrict__ pre)
{
    __shared__ short Ahi[128 * PK], Alo[128 * PK];
    __shared__ short Bhi[128 * PK], Blo[128 * PK];

    const int tid  = threadIdx.x;
    const int m0   = blockIdx.y * 128, n0 = blockIdx.x * 128;
    const int am = tid >> 1, ak = (tid & 1) << 4;
    const int bn = (tid & 31) << 2, bk = tid >> 5;
    const int lane = tid & 63, wv = tid >> 6;
    const int wrow = (wv >> 1) * 64, wcol = (wv & 1) * 64;
    const int lm = lane & 15, q = lane >> 4;

    f32x4 acc[4][4];
    #pragma unroll
    for (int i = 0; i < 4; i++)
        #pragma unroll
        for (int j = 0; j < 4; j++) acc[i][j] = (f32x4){0.f, 0.f, 0.f, 0.f};

    const float* pA0 = x + (size_t)(m0 + am) * KD + ak;
    const float* pB0 = W + (size_t)bk * 4 * DSAE + n0 + bn;

    for (int k0 = 0; k0 < KD; k0 += 32) {
        {
            const float* pA = pA0 + k0;
            float f[16];
            *(float4*)&f[0]  = *(const float4*)(pA);
            *(float4*)&f[4]  = *(const float4*)(pA + 4);
            *(float4*)&f[8]  = *(const float4*)(pA + 8);
            *(float4*)&f[12] = *(const float4*)(pA + 12);
            unsigned hw[8], lw[8];
            #pragma unroll
            for (int j = 0; j < 8; j++) {
                float a = f[2*j], b = f[2*j+1];
                float ha = hi_part(a), hb = hi_part(b);
                hw[j] = pack2(ha, hb);
                lw[j] = pack2(a - ha, b - hb);
            }
            short* dh = &Ahi[am * PK + ak];
            short* dl = &Alo[am * PK + ak];
            *(int4*)dh       = *(int4*)&hw[0];
            *(int4*)(dh + 8) = *(int4*)&hw[4];
            *(int4*)dl       = *(int4*)&lw[0];
            *(int4*)(dl + 8) = *(int4*)&lw[4];
        }
        {
            const float* pB = pB0 + (size_t)k0 * DSAE;
            float4 w0 = *(const float4*)(pB);
            float4 w1 = *(const float4*)(pB + DSAE);
            float4 w2 = *(const float4*)(pB + 2 * DSAE);
            float4 w3 = *(const float4*)(pB + 3 * DSAE);
            float fr[4][4] = {{w0.x,w0.y,w0.z,w0.w},{w1.x,w1.y,w1.z,w1.w},
                              {w2.x,w2.y,w2.z,w2.w},{w3.x,w3.y,w3.z,w3.w}};
            #pragma unroll
            for (int c = 0; c < 4; c++) {
                float h0 = hi_part(fr[0][c]), h1 = hi_part(fr[1][c]);
                float h2 = hi_part(fr[2][c]), h3 = hi_part(fr[3][c]);
                unsigned hh[2] = { pack2(h0, h1), pack2(h2, h3) };
                unsigned ll[2] = { pack2(fr[0][c]-h0, fr[1][c]-h1), pack2(fr[2][c]-h2, fr[3][c]-h3) };
                *(int2*)&Bhi[(bn + c) * PK + bk * 4] = *(int2*)&hh[0];
                *(int2*)&Blo[(bn + c) * PK + bk * 4] = *(int2*)&ll[0];
            }
        }
        __syncthreads();

        frag ah[4], al[4], bh[4], bl[4];
        #pragma unroll
        for (int t4 = 0; t4 < 4; t4++) {
            int r = (wrow + t4 * 16 + lm) * PK + q * 8;
            ah[t4] = *(const frag*)&Ahi[r];
            al[t4] = *(const frag*)&Alo[r];
            int cIdx = (wcol + t4 * 16 + lm) * PK + q * 8;
            bh[t4] = *(const frag*)&Bhi[cIdx];
            bl[t4] = *(const frag*)&Blo[cIdx];
        }
        #pragma unroll
        for (int mt = 0; mt < 4; mt++)
            #pragma unroll
            for (int nt = 0; nt < 4; nt++) {
                acc[mt][nt] = __builtin_amdgcn_mfma_f32_16x16x32_bf16(ah[mt], bh[nt], acc[mt][nt], 0, 0, 0);
                acc[mt][nt] = __builtin_amdgcn_mfma_f32_16x16x32_bf16(ah[mt], bl[nt], acc[mt][nt], 0, 0, 0);
                acc[mt][nt] = __builtin_amdgcn_mfma_f32_16x16x32_bf16(al[mt], bh[nt], acc[mt][nt], 0, 0, 0);
            }
        __syncthreads();
    }

    #pragma unroll
    for (int mt = 0; mt < 4; mt++)
        #pragma unroll
        for (int nt = 0; nt < 4; nt++) {
            int col = n0 + wcol + nt * 16 + lm;
            float bv = benc[col];
            #pragma unroll
            for (int r = 0; r < 4; r++) {
                int row = m0 + wrow + mt * 16 + q * 4 + r;
                pre[(size_t)row * DSAE + col] = acc[mt][nt][r] + bv;
            }
        }
}

// ---------------------------------------------------------------- K2: exact top-32 selection (one block per row)
__global__ __launch_bounds__(256) void select_topk(float* __restrict__ zout,
                                                   const float* __restrict__ x,
                                                   const float* __restrict__ W,
                                                   int* __restrict__ widx_g,
                                                   float* __restrict__ wval_g,
                                                   float mgn)
{
    const int b   = blockIdx.x;
    const int tid = threadIdx.x;

    __shared__ float vals[DSAE];            // 32 KB
    __shared__ unsigned char flag[DSAE];    // 8 KB
    __shared__ float rv[256];  __shared__ int ri[256];
    __shared__ double dred[256];
    __shared__ float topv[TOPK]; __shared__ int topi[TOPK];
    __shared__ int wix[64]; __shared__ double wdv[64]; __shared__ unsigned char wsel[64];
    __shared__ int wcnt, nabove, outc;

    float* zrow = zout + (size_t)b * DSAE;
    #pragma unroll
    for (int p = 0; p < DSAE / 256; p++) vals[tid + p * 256] = zrow[tid + p * 256];
    __syncthreads();

    for (int pass = 0; pass < TOPK; pass++) {
        float bv = -FLT_MAX; int bi = 0x7fffffff;
        #pragma unroll
        for (int p = 0; p < DSAE / 256; p++) {
            int i = tid + p * 256;
            float v = vals[i];
            if (v > bv) { bv = v; bi = i; }
        }
        rv[tid] = bv; ri[tid] = bi; __syncthreads();
        for (int s = 128; s > 0; s >>= 1) {
            if (tid < s) {
                if (rv[tid + s] > rv[tid] || (rv[tid + s] == rv[tid] && ri[tid + s] < ri[tid])) {
                    rv[tid] = rv[tid + s]; ri[tid] = ri[tid + s];
                }
            }
            __syncthreads();
        }
        if (tid == 0) { topv[pass] = rv[0]; topi[pass] = ri[0]; vals[ri[0]] = -FLT_MAX; }
        __syncthreads();
    }
    if (tid < TOPK) vals[topi[tid]] = topv[tid];
    if (tid == 0) { wcnt = 0; nabove = 0; outc = 0; }
    __syncthreads();

    const float v32 = topv[TOPK - 1];

    for (int p = 0; p < DSAE / 256; p++) {
        int i = tid + p * 256;
        float v = vals[i];
        if (v > v32 + mgn) { atomicAdd(&nabove, 1); }
        else if (v >= v32 - mgn) { int slot = atomicAdd(&wcnt, 1); if (slot < 64) wix[slot] = i; }
    }
    __syncthreads();
    const int nw   = wcnt < 64 ? wcnt : 64;
    const int need = TOPK - nabove;

    if (nw == need) {
        if (tid < 64) wsel[tid] = (tid < nw) ? 1 : 0;
    } else {
        // fp64-exact re-computation of window atoms (rare)
        const float* xr = x + (size_t)b * KD;
        for (int w = 0; w < nw; w++) {
            const int s = wix[w];
            double part = 0.0;
            for (int kk = tid; kk < KD; kk += 256)
                part += (double)xr[kk] * (double)W[(size_t)kk * DSAE + s];
            dred[tid] = part; __syncthreads();
            for (int st = 128; st > 0; st >>= 1) { if (tid < st) dred[tid] += dred[tid + st]; __syncthreads(); }
            if (tid == 0) wdv[w] = dred[0];
            __syncthreads();
        }
        if (tid < 64) {
            unsigned char sel = 0;
            if (tid < nw) {
                int rank = 0;
                double mv = wdv[tid]; int mi = wix[tid];
                for (int w2 = 0; w2 < nw; w2++)
                    if (wdv[w2] > mv || (wdv[w2] == mv && wix[w2] < mi)) rank++;
                sel = (rank < need) ? 1 : 0;
            }
            wsel[tid] = sel;
        }
    }
    __syncthreads();

    for (int p = 0; p < DSAE / 256; p++) flag[tid + p * 256] = 0;
    __syncthreads();
    for (int p = 0; p < DSAE / 256; p++) {
        int i = tid + p * 256;
        if (vals[i] > v32 + mgn) flag[i] = 1;
    }
    if (tid < nw && wsel[tid]) flag[wix[tid]] = 1;
    __syncthreads();

    for (int p = 0; p < DSAE / 256; p++) {
        int i = tid + p * 256;
        float v = vals[i];
        float zv = 0.f;
        if (flag[i]) {
            zv = v > 0.f ? v : 0.f;
            int slot = atomicAdd(&outc, 1);
            if (slot < TOPK) { widx_g[b * TOPK + slot] = i; wval_g[b * TOPK + slot] = zv; }
        }
        zrow[i] = zv;
    }
}

// ---------------------------------------------------------------- K3: sparse decode + fused loss (one block per sample)
__global__ __launch_bounds__(256) void decode_loss(const int* __restrict__ widx_g,
                                                   const float* __restrict__ wval_g,
                                                   const float* __restrict__ Wdec,
                                                   const float* __restrict__ bdec,
                                                   const float* __restrict__ x,
                                                   float* __restrict__ xhat,
                                                   double* __restrict__ acc)
{
    const int b = blockIdx.x, tid = threadIdx.x;
    __shared__ int sidx[TOPK]; __shared__ float sval[TOPK];
    __shared__ double dred[256];
    if (tid < TOPK) { sidx[tid] = widx_g[b * TOPK + tid]; sval[tid] = wval_g[b * TOPK + tid]; }
    __syncthreads();

    float o[KD / 256];
    #pragma unroll
    for (int c = 0; c < KD / 256; c++) o[c] = bdec[tid + c * 256];

    for (int j = 0; j < TOPK; j++) {
        float v = sval[j];
        const float* wr = Wdec + (size_t)sidx[j] * KD + tid;
        #pragma unroll
        for (int c = 0; c < KD / 256; c++) o[c] = fmaf(v, wr[c * 256], o[c]);
    }

    double ls = 0.0;
    const float* xr = x + (size_t)b * KD;
    float* xo = xhat + (size_t)b * KD;
    #pragma unroll
    for (int c = 0; c < KD / 256; c++) {
        int e = tid + c * 256;
        float ov = o[c];
        float d  = ov - xr[e];
        ls += (double)d * (double)d;
        xo[e] = ov;
    }
    dred[tid] = ls; __syncthreads();
    for (int s = 128; s > 0; s >>= 1) { if (tid < s) dred[tid] += dred[tid + s]; __syncthreads(); }
    if (tid == 0) atomicAdd(acc, dred[0]);
}

// ---------------------------------------------------------------- K4: finalize
__global__ void finalize(const double* __restrict__ acc, float* __restrict__ out)
{
    if (threadIdx.x == 0) out[0] = (float)(*acc / (double)(B_ * T_));
}

// ----------------------------------------------------------------
extern "C" void kernel_launch(void* const* d_in, const int* in_sizes, int n_in,
                              void* d_out, int out_size, void* d_ws, size_t ws_size,
                              hipStream_t stream)
{
    (void)in_sizes; (void)n_in; (void)out_size;
    const float* x    = (const float*)d_in[0];
    const float* Wenc = (const float*)d_in[1];
    const float* Wdec = (const float*)d_in[2];
    const float* benc = (const float*)d_in[3];
    const float* bdec = (const float*)d_in[4];

    float*  out    = (float*)d_out;
    double* acc    = (double*)d_ws;
    int*    widx_g = (int*)((char*)d_ws + 16);
    float*  wval_g = (float*)((char*)d_ws + 16 + (size_t)B_ * TOPK * 4);

    // fast-path workspace layout
    const size_t XC_OFF = (size_t)1 << 20;                       // Xh: 1024*3072*2  = 6.3 MB
    const size_t WT_OFF = (size_t)8 << 20;                       // Wt: 8192*6144*2  = 100.7 MB
    const size_t NEED   = WT_OFF + (size_t)DSAE * (2 * KD) * 2;  // ~109 MB
    const bool fast = (ws_size >= NEED);

    float* pre  = out + Z_OFF;     // z region doubles as the dense pre buffer
    float* xhat = out + XHAT_OFF;

    hipLaunchKernelGGL(zero_acc, dim3(1), dim3(1), 0, stream, acc);

    if (fast) {
        ushort* Xh = (ushort*)((char*)d_ws + XC_OFF);
        ushort* Wt = (ushort*)((char*)d_ws + WT_OFF);
        hipLaunchKernelGGL(convert_x,   dim3(3, B_),            dim3(256), 0, stream, x, Xh);
        hipLaunchKernelGGL(convert_wT,  dim3(DSAE/32, KD/64),   dim3(256), 0, stream, Wenc, Wt);
        hipLaunchKernelGGL(encode_gemm, dim3(DSAE/128, B_/128), dim3(256), 0, stream, Xh, Wt, benc, pre);
    } else {
        hipLaunchKernelGGL(encode_mfma, dim3(DSAE/128, B_/128), dim3(256), 0, stream, x, Wenc, benc, pre);
    }

    // margin: ~16 sigma of fp16 2-product GEMM error (5e-3) on fast path, 2e-3 (bf16x2) on fallback
    hipLaunchKernelGGL(select_topk, dim3(B_), dim3(256), 0, stream, pre, x, Wenc, widx_g, wval_g,
                       fast ? 5e-3f : 2e-3f);
    hipLaunchKernelGGL(decode_loss, dim3(B_), dim3(256), 0, stream, widx_g, wval_g, Wdec, bdec, x, xhat, acc);
    hipLaunchKernelGGL(finalize,    dim3(1),  dim3(1),   0, stream, acc, out);
}

// Round 2
// 449.753 us; speedup vs baseline: 1.4928x; 1.2510x over previous
//
#include <hip/hip_runtime.h>
#include <hip/hip_fp16.h>
#include <cfloat>

#define B_    1024
#define T_    4
#define DIN   768
#define KD    3072      // T_*DIN, contracted dim of encoder
#define DSAE  8192
#define TOPK  32

static constexpr size_t XHAT_OFF = 1;
static constexpr size_t Z_OFF    = 1 + (size_t)B_ * T_ * DIN;   // 3145729

typedef __attribute__((ext_vector_type(8))) short    frag;    // 8 bf16 = 4 VGPRs (legacy path)
typedef __attribute__((ext_vector_type(8))) _Float16 hfrag;   // 8 fp16 = 4 VGPRs
typedef __attribute__((ext_vector_type(4))) float    f32x4;   // MFMA C/D

__device__ __forceinline__ unsigned pack2(float a, float b) {
    return (__builtin_bit_cast(unsigned, a) >> 16) | (__builtin_bit_cast(unsigned, b) & 0xFFFF0000u);
}
__device__ __forceinline__ float hi_part(float a) {
    return __builtin_bit_cast(float, __builtin_bit_cast(unsigned, a) & 0xFFFF0000u);
}

// ---------------------------------------------------------------- K0
__global__ void zero_acc(double* acc) { if (threadIdx.x == 0) *acc = 0.0; }

// ---------------------------------------------------------------- FAST PATH: convert kernels
__global__ __launch_bounds__(256) void convert_x(const float* __restrict__ x, ushort* __restrict__ Xh)
{
    const int row = blockIdx.y;
    const int col = blockIdx.x * 1024 + threadIdx.x * 4;
    const float4 f = *(const float4*)(x + (size_t)row * KD + col);
    ushort4 h;
    h.x = __half_as_ushort(__float2half(f.x));
    h.y = __half_as_ushort(__float2half(f.y));
    h.z = __half_as_ushort(__float2half(f.z));
    h.w = __half_as_ushort(__float2half(f.w));
    *(ushort4*)(Xh + (size_t)row * KD + col) = h;
}

// Wt[n][0..3071]    = fp16(W[k][n])                 (transposed hi)
// Wt[n][3072..6143] = fp16((W[k][n]-hi)*2048)       (transposed scaled residual)
__global__ __launch_bounds__(256) void convert_wT(const float* __restrict__ W, ushort* __restrict__ Wt)
{
    __shared__ float t[64][33];
    const int tx = threadIdx.x & 31, ty = threadIdx.x >> 5;
    const int n0 = blockIdx.x * 32, k0 = blockIdx.y * 64;
    #pragma unroll
    for (int j = 0; j < 8; j++)
        t[ty + j * 8][tx] = W[(size_t)(k0 + ty + j * 8) * DSAE + n0 + tx];
    __syncthreads();
    #pragma unroll
    for (int j = 0; j < 4; j++) {
        const int nl = ty + j * 8;
        const float a = t[tx * 2][nl], b = t[tx * 2 + 1][nl];
        const __half ha = __float2half(a), hb = __float2half(b);
        const float ra = (a - __half2float(ha)) * 2048.0f;
        const float rb = (b - __half2float(hb)) * 2048.0f;
        const ushort2 hv = make_ushort2(__half_as_ushort(ha), __half_as_ushort(hb));
        const ushort2 lv = make_ushort2(__half_as_ushort(__float2half(ra)),
                                        __half_as_ushort(__float2half(rb)));
        ushort* dst = Wt + (size_t)(n0 + nl) * (2 * KD) + k0 + tx * 2;
        *(ushort2*)dst        = hv;
        *(ushort2*)(dst + KD) = lv;
    }
}

// ---------------------------------------------------------------- FAST PATH: fp16 2-product MFMA GEMM
__device__ __forceinline__ void gload16(const ushort* g, ushort* l)
{
    __builtin_amdgcn_global_load_lds((const __attribute__((address_space(1))) void*)g,
                                     (__attribute__((address_space(3))) void*)l, 16, 0, 0);
}

__global__ __launch_bounds__(256, 2) void encode_gemm(const ushort* __restrict__ Xh,
                                                      const ushort* __restrict__ Wt,
                                                      const float* __restrict__ benc,
                                                      float* __restrict__ pre)
{
    __shared__ ushort As [128 * 32];   // [m][k] 8 KB
    __shared__ ushort Bhs[128 * 32];   // [n][k] hi
    __shared__ ushort Bls[128 * 32];   // [n][k] lo'

    const int tid  = threadIdx.x;
    const int n0   = blockIdx.x * 128, m0 = blockIdx.y * 128;
    const int lane = tid & 63, wv = tid >> 6;
    const int wrow = (wv >> 1) * 64, wcol = (wv & 1) * 64;
    const int lm = lane & 15, q = lane >> 4;

    f32x4 acc[4][4], acc2[4][4];
    #pragma unroll
    for (int i = 0; i < 4; i++)
        #pragma unroll
        for (int j = 0; j < 4; j++) { acc[i][j] = (f32x4){0.f,0.f,0.f,0.f}; acc2[i][j] = (f32x4){0.f,0.f,0.f,0.f}; }

    const int srow = lane >> 2, scol = (lane & 3) * 8;
    const ushort* pa0 = Xh + (size_t)(m0 + wv * 16 + srow) * KD + scol;
    const ushort* pa1 = pa0 + (size_t)64 * KD;
    const ushort* pb0 = Wt + (size_t)(n0 + wv * 16 + srow) * (2 * KD) + scol;
    const ushort* pb1 = pb0 + (size_t)64 * (2 * KD);
    ushort* da0 = &As [wv * 512]; ushort* da1 = &As [2048 + wv * 512];
    ushort* dh0 = &Bhs[wv * 512]; ushort* dh1 = &Bhs[2048 + wv * 512];
    ushort* dl0 = &Bls[wv * 512]; ushort* dl1 = &Bls[2048 + wv * 512];

    for (int k0 = 0; k0 < KD; k0 += 32) {
        gload16(pa0 + k0,      da0);
        gload16(pa1 + k0,      da1);
        gload16(pb0 + k0,      dh0);
        gload16(pb1 + k0,      dh1);
        gload16(pb0 + KD + k0, dl0);
        gload16(pb1 + KD + k0, dl1);
        __syncthreads();

        hfrag af[4], bh[4], bl[4];
        #pragma unroll
        for (int t4 = 0; t4 < 4; t4++) {
            af[t4] = *(const hfrag*)&As [(wrow + t4 * 16 + lm) * 32 + q * 8];
            bh[t4] = *(const hfrag*)&Bhs[(wcol + t4 * 16 + lm) * 32 + q * 8];
            bl[t4] = *(const hfrag*)&Bls[(wcol + t4 * 16 + lm) * 32 + q * 8];
        }
        #pragma unroll
        for (int mt = 0; mt < 4; mt++)
            #pragma unroll
            for (int nt = 0; nt < 4; nt++) {
                acc [mt][nt] = __builtin_amdgcn_mfma_f32_16x16x32_f16(af[mt], bh[nt], acc [mt][nt], 0, 0, 0);
                acc2[mt][nt] = __builtin_amdgcn_mfma_f32_16x16x32_f16(af[mt], bl[nt], acc2[mt][nt], 0, 0, 0);
            }
        __syncthreads();
    }

    #pragma unroll
    for (int mt = 0; mt < 4; mt++)
        #pragma unroll
        for (int nt = 0; nt < 4; nt++) {
            const int col = n0 + wcol + nt * 16 + lm;
            const float bv = benc[col];
            #pragma unroll
            for (int r = 0; r < 4; r++) {
                const int row = m0 + wrow + mt * 16 + q * 4 + r;
                pre[(size_t)row * DSAE + col] = acc[mt][nt][r] + 4.8828125e-4f * acc2[mt][nt][r] + bv;
            }
        }
}

// ---------------------------------------------------------------- FALLBACK: bf16x2-split MFMA GEMM (unchanged)
#define PK 40
__global__ __launch_bounds__(256, 2) void encode_mfma(const float* __restrict__ x,
                                                      const float* __restrict__ W,
                                                      const float* __restrict__ benc,
                                                      float* __restrict__ pre)
{
    __shared__ short Ahi[128 * PK], Alo[128 * PK];
    __shared__ short Bhi[128 * PK], Blo[128 * PK];

    const int tid  = threadIdx.x;
    const int m0   = blockIdx.y * 128, n0 = blockIdx.x * 128;
    const int am = tid >> 1, ak = (tid & 1) << 4;
    const int bn = (tid & 31) << 2, bk = tid >> 5;
    const int lane = tid & 63, wv = tid >> 6;
    const int wrow = (wv >> 1) * 64, wcol = (wv & 1) * 64;
    const int lm = lane & 15, q = lane >> 4;

    f32x4 acc[4][4];
    #pragma unroll
    for (int i = 0; i < 4; i++)
        #pragma unroll
        for (int j = 0; j < 4; j++) acc[i][j] = (f32x4){0.f, 0.f, 0.f, 0.f};

    const float* pA0 = x + (size_t)(m0 + am) * KD + ak;
    const float* pB0 = W + (size_t)bk * 4 * DSAE + n0 + bn;

    for (int k0 = 0; k0 < KD; k0 += 32) {
        {
            const float* pA = pA0 + k0;
            float f[16];
            *(float4*)&f[0]  = *(const float4*)(pA);
            *(float4*)&f[4]  = *(const float4*)(pA + 4);
            *(float4*)&f[8]  = *(const float4*)(pA + 8);
            *(float4*)&f[12] = *(const float4*)(pA + 12);
            unsigned hw[8], lw[8];
            #pragma unroll
            for (int j = 0; j < 8; j++) {
                float a = f[2*j], b = f[2*j+1];
                float ha = hi_part(a), hb = hi_part(b);
                hw[j] = pack2(ha, hb);
                lw[j] = pack2(a - ha, b - hb);
            }
            short* dh = &Ahi[am * PK + ak];
            short* dl = &Alo[am * PK + ak];
            *(int4*)dh       = *(int4*)&hw[0];
            *(int4*)(dh + 8) = *(int4*)&hw[4];
            *(int4*)dl       = *(int4*)&lw[0];
            *(int4*)(dl + 8) = *(int4*)&lw[4];
        }
        {
            const float* pB = pB0 + (size_t)k0 * DSAE;
            float4 w0 = *(const float4*)(pB);
            float4 w1 = *(const float4*)(pB + DSAE);
            float4 w2 = *(const float4*)(pB + 2 * DSAE);
            float4 w3 = *(const float4*)(pB + 3 * DSAE);
            float fr[4][4] = {{w0.x,w0.y,w0.z,w0.w},{w1.x,w1.y,w1.z,w1.w},
                              {w2.x,w2.y,w2.z,w2.w},{w3.x,w3.y,w3.z,w3.w}};
            #pragma unroll
            for (int c = 0; c < 4; c++) {
                float h0 = hi_part(fr[0][c]), h1 = hi_part(fr[1][c]);
                float h2 = hi_part(fr[2][c]), h3 = hi_part(fr[3][c]);
                unsigned hh[2] = { pack2(h0, h1), pack2(h2, h3) };
                unsigned ll[2] = { pack2(fr[0][c]-h0, fr[1][c]-h1), pack2(fr[2][c]-h2, fr[3][c]-h3) };
                *(int2*)&Bhi[(bn + c) * PK + bk * 4] = *(int2*)&hh[0];
                *(int2*)&Blo[(bn + c) * PK + bk * 4] = *(int2*)&ll[0];
            }
        }
        __syncthreads();

        frag ah[4], al[4], bh[4], bl[4];
        #pragma unroll
        for (int t4 = 0; t4 < 4; t4++) {
            int r = (wrow + t4 * 16 + lm) * PK + q * 8;
            ah[t4] = *(const frag*)&Ahi[r];
            al[t4] = *(const frag*)&Alo[r];
            int cIdx = (wcol + t4 * 16 + lm) * PK + q * 8;
            bh[t4] = *(const frag*)&Bhi[cIdx];
            bl[t4] = *(const frag*)&Blo[cIdx];
        }
        #pragma unroll
        for (int mt = 0; mt < 4; mt++)
            #pragma unroll
            for (int nt = 0; nt < 4; nt++) {
                acc[mt][nt] = __builtin_amdgcn_mfma_f32_16x16x32_bf16(ah[mt], bh[nt], acc[mt][nt], 0, 0, 0);
                acc[mt][nt] = __builtin_amdgcn_mfma_f32_16x16x32_bf16(ah[mt], bl[nt], acc[mt][nt], 0, 0, 0);
                acc[mt][nt] = __builtin_amdgcn_mfma_f32_16x16x32_bf16(al[mt], bh[nt], acc[mt][nt], 0, 0, 0);
            }
        __syncthreads();
    }

    #pragma unroll
    for (int mt = 0; mt < 4; mt++)
        #pragma unroll
        for (int nt = 0; nt < 4; nt++) {
            int col = n0 + wcol + nt * 16 + lm;
            float bv = benc[col];
            #pragma unroll
            for (int r = 0; r < 4; r++) {
                int row = m0 + wrow + mt * 16 + q * 4 + r;
                pre[(size_t)row * DSAE + col] = acc[mt][nt][r] + bv;
            }
        }
}

// ---------------------------------------------------------------- K2: exact top-32 selection (candidate-prune)
// Old: 32 serial max-passes (~256 barriers/block) -> latency-bound, 180 us.
// New: 32nd-largest of per-thread maxima is a provable lower bound on v32
// (top-32 local maxima are 32 distinct elements) -> compact ~35 candidates,
// rank-count them in parallel. ~10 barriers/block.
__global__ __launch_bounds__(256) void select_topk(float* __restrict__ zout,
                                                   const float* __restrict__ x,
                                                   const float* __restrict__ W,
                                                   const ushort* __restrict__ Wt,  // fp16 hi/lo transposed copy (may be null)
                                                   int* __restrict__ widx_g,
                                                   float* __restrict__ wval_g,
                                                   float mgn)
{
    const int b   = blockIdx.x;
    const int tid = threadIdx.x;

    __shared__ float vals[DSAE];            // 32 KB
    __shared__ unsigned char flag[DSAE];    // 8 KB
    __shared__ float lmax[256];
    __shared__ float cand_v[512]; __shared__ int cand_i[512];   // 4 KB
    __shared__ float rv[256];  __shared__ int ri[256];
    __shared__ double dred[256];
    __shared__ float topv[TOPK]; __shared__ int topi[TOPK];
    __shared__ int wix[64]; __shared__ double wdv[64]; __shared__ unsigned char wsel[64];
    __shared__ int wcnt, nabove, outc, ncand;
    __shared__ float sL, sv32;

    float* zrow = zout + (size_t)b * DSAE;

    // load row to LDS, tracking per-thread max
    float lm = -FLT_MAX;
    #pragma unroll
    for (int p = 0; p < DSAE / 256; p++) {
        float v = zrow[tid + p * 256];
        vals[tid + p * 256] = v;
        lm = fmaxf(lm, v);
    }
    lmax[tid] = lm;
    if (tid == 0) { ncand = 0; wcnt = 0; nabove = 0; outc = 0; }
    __syncthreads();

    // rank this thread's max among the 256 (desc, index tiebreak) -> L = 32nd largest
    {
        int rk = 0;
        for (int j = 0; j < 256; j++) {
            float o = lmax[j];
            rk += (o > lm || (o == lm && j < tid)) ? 1 : 0;
        }
        if (rk == TOPK - 1) sL = lm;
    }
    __syncthreads();
    const float L = sL;

    // compact strict candidates (v > L); top-32 guaranteed inside when >=32 exist
    for (int p = 0; p < DSAE / 256; p++) {
        int i = tid + p * 256;
        float v = vals[i];
        if (v > L) {
            int s = atomicAdd(&ncand, 1);
            if (s < 512) { cand_v[s] = v; cand_i[s] = i; }
        }
    }
    __syncthreads();
    const int ncg = ncand;

    if (ncg < TOPK) {
        // fewer than 32 strictly above L, and >=32 elements are >= L  =>  v32 == L
        if (tid == 0) sv32 = L;
    } else if (ncg <= 512) {
        // exact rank-count among candidates (value desc, index tiebreak)
        for (int j = tid; j < ncg; j += 256) {
            float v = cand_v[j]; int idx = cand_i[j];
            int r = 0;
            for (int k2 = 0; k2 < ncg; k2++) {
                float o = cand_v[k2];
                r += (o > v || (o == v && cand_i[k2] < idx)) ? 1 : 0;
            }
            if (r == TOPK - 1) sv32 = v;
        }
    } else {
        // degenerate (massive ties): original destructive 32-pass selection + restore
        for (int pass = 0; pass < TOPK; pass++) {
            float bv = -FLT_MAX; int bi = 0x7fffffff;
            for (int p = 0; p < DSAE / 256; p++) {
                int i = tid + p * 256;
                float v = vals[i];
                if (v > bv) { bv = v; bi = i; }
            }
            rv[tid] = bv; ri[tid] = bi; __syncthreads();
            for (int s = 128; s > 0; s >>= 1) {
                if (tid < s) {
                    if (rv[tid + s] > rv[tid] || (rv[tid + s] == rv[tid] && ri[tid + s] < ri[tid])) {
                        rv[tid] = rv[tid + s]; ri[tid] = ri[tid + s];
                    }
                }
                __syncthreads();
            }
            if (tid == 0) { topv[pass] = rv[0]; topi[pass] = ri[0]; vals[ri[0]] = -FLT_MAX; }
            __syncthreads();
        }
        if (tid < TOPK) vals[topi[tid]] = topv[tid];
        if (tid == 0) sv32 = topv[TOPK - 1];
    }
    __syncthreads();
    const float v32 = sv32;

    // margin window around v32 (GEMM-error tolerance), exact tie-break inside
    for (int p = 0; p < DSAE / 256; p++) {
        int i = tid + p * 256;
        float v = vals[i];
        if (v > v32 + mgn) { atomicAdd(&nabove, 1); }
        else if (v >= v32 - mgn) { int slot = atomicAdd(&wcnt, 1); if (slot < 64) wix[slot] = i; }
    }
    __syncthreads();
    const int nw   = wcnt < 64 ? wcnt : 64;
    const int need = TOPK - nabove;

    if (nw == need) {
        if (tid < 64) wsel[tid] = (tid < nw) ? 1 : 0;
    } else {
        // high-precision re-computation of window atoms.
        // Fast path: coalesced fp16 hi+lo rows of Wt (reconstruction err ~5e-7,
        // well below the fp32-reference's own ~1e-5 noise). Fallback: exact W column.
        const float* xr = x + (size_t)b * KD;
        for (int w = 0; w < nw; w++) {
            const int s = wix[w];
            double part = 0.0;
            if (Wt) {
                const ushort* wr = Wt + (size_t)s * (2 * KD);
                for (int kk = tid; kk < KD; kk += 256) {
                    double wvd = (double)__half2float(__ushort_as_half(wr[kk]))
                               + (double)__half2float(__ushort_as_half(wr[kk + KD])) * (1.0 / 2048.0);
                    part += (double)xr[kk] * wvd;
                }
            } else {
                for (int kk = tid; kk < KD; kk += 256)
                    part += (double)xr[kk] * (double)W[(size_t)kk * DSAE + s];
            }
            dred[tid] = part; __syncthreads();
            for (int st = 128; st > 0; st >>= 1) { if (tid < st) dred[tid] += dred[tid + st]; __syncthreads(); }
            if (tid == 0) wdv[w] = dred[0];
            __syncthreads();
        }
        if (tid < 64) {
            unsigned char sel = 0;
            if (tid < nw) {
                int rank = 0;
                double mv = wdv[tid]; int mi = wix[tid];
                for (int w2 = 0; w2 < nw; w2++)
                    if (wdv[w2] > mv || (wdv[w2] == mv && wix[w2] < mi)) rank++;
                sel = (rank < need) ? 1 : 0;
            }
            wsel[tid] = sel;
        }
    }
    __syncthreads();

    for (int p = 0; p < DSAE / 256; p++) flag[tid + p * 256] = 0;
    __syncthreads();
    for (int p = 0; p < DSAE / 256; p++) {
        int i = tid + p * 256;
        if (vals[i] > v32 + mgn) flag[i] = 1;
    }
    if (tid < nw && wsel[tid]) flag[wix[tid]] = 1;
    __syncthreads();

    for (int p = 0; p < DSAE / 256; p++) {
        int i = tid + p * 256;
        float v = vals[i];
        float zv = 0.f;
        if (flag[i]) {
            zv = v > 0.f ? v : 0.f;
            int slot = atomicAdd(&outc, 1);
            if (slot < TOPK) { widx_g[b * TOPK + slot] = i; wval_g[b * TOPK + slot] = zv; }
        }
        zrow[i] = zv;
    }
}

// ---------------------------------------------------------------- K3: sparse decode + fused loss (float4 loads)
__global__ __launch_bounds__(256) void decode_loss(const int* __restrict__ widx_g,
                                                   const float* __restrict__ wval_g,
                                                   const float* __restrict__ Wdec,
                                                   const float* __restrict__ bdec,
                                                   const float* __restrict__ x,
                                                   float* __restrict__ xhat,
                                                   double* __restrict__ acc)
{
    const int b = blockIdx.x, tid = threadIdx.x;
    __shared__ int sidx[TOPK]; __shared__ float sval[TOPK];
    __shared__ double dred[256];
    if (tid < TOPK) { sidx[tid] = widx_g[b * TOPK + tid]; sval[tid] = wval_g[b * TOPK + tid]; }
    __syncthreads();

    float4 o[3];
    #pragma unroll
    for (int c = 0; c < 3; c++) o[c] = ((const float4*)bdec)[tid + c * 256];

    for (int j = 0; j < TOPK; j++) {
        const float v = sval[j];
        const float4* wr = (const float4*)(Wdec + (size_t)sidx[j] * KD);
        #pragma unroll
        for (int c = 0; c < 3; c++) {
            float4 w = wr[tid + c * 256];
            o[c].x = fmaf(v, w.x, o[c].x);
            o[c].y = fmaf(v, w.y, o[c].y);
            o[c].z = fmaf(v, w.z, o[c].z);
            o[c].w = fmaf(v, w.w, o[c].w);
        }
    }

    double ls = 0.0;
    const float4* xr = (const float4*)(x + (size_t)b * KD);
    float* xo = xhat + (size_t)b * KD;     // offset 4 mod 16 -> scalar stores
    #pragma unroll
    for (int c = 0; c < 3; c++) {
        float4 xv = xr[tid + c * 256];
        float4 ov = o[c];
        float d0 = ov.x - xv.x, d1 = ov.y - xv.y, d2 = ov.z - xv.z, d3 = ov.w - xv.w;
        ls += (double)d0 * (double)d0 + (double)d1 * (double)d1
            + (double)d2 * (double)d2 + (double)d3 * (double)d3;
        const int e = (tid + c * 256) * 4;
        xo[e] = ov.x; xo[e + 1] = ov.y; xo[e + 2] = ov.z; xo[e + 3] = ov.w;
    }
    dred[tid] = ls; __syncthreads();
    for (int s = 128; s > 0; s >>= 1) { if (tid < s) dred[tid] += dred[tid + s]; __syncthreads(); }
    if (tid == 0) atomicAdd(acc, dred[0]);
}

// ---------------------------------------------------------------- K4: finalize
__global__ void finalize(const double* __restrict__ acc, float* __restrict__ out)
{
    if (threadIdx.x == 0) out[0] = (float)(*acc / (double)(B_ * T_));
}

// ----------------------------------------------------------------
extern "C" void kernel_launch(void* const* d_in, const int* in_sizes, int n_in,
                              void* d_out, int out_size, void* d_ws, size_t ws_size,
                              hipStream_t stream)
{
    (void)in_sizes; (void)n_in; (void)out_size;
    const float* x    = (const float*)d_in[0];
    const float* Wenc = (const float*)d_in[1];
    const float* Wdec = (const float*)d_in[2];
    const float* benc = (const float*)d_in[3];
    const float* bdec = (const float*)d_in[4];

    float*  out    = (float*)d_out;
    double* acc    = (double*)d_ws;
    int*    widx_g = (int*)((char*)d_ws + 16);
    float*  wval_g = (float*)((char*)d_ws + 16 + (size_t)B_ * TOPK * 4);

    // fast-path workspace layout
    const size_t XC_OFF = (size_t)1 << 20;                       // Xh: 1024*3072*2  = 6.3 MB
    const size_t WT_OFF = (size_t)8 << 20;                       // Wt: 8192*6144*2  = 100.7 MB
    const size_t NEED   = WT_OFF + (size_t)DSAE * (2 * KD) * 2;  // ~109 MB
    const bool fast = (ws_size >= NEED);

    float* pre  = out + Z_OFF;     // z region doubles as the dense pre buffer
    float* xhat = out + XHAT_OFF;

    hipLaunchKernelGGL(zero_acc, dim3(1), dim3(1), 0, stream, acc);

    ushort* Xh = (ushort*)((char*)d_ws + XC_OFF);
    ushort* Wt = (ushort*)((char*)d_ws + WT_OFF);
    if (fast) {
        hipLaunchKernelGGL(convert_x,   dim3(3, B_),            dim3(256), 0, stream, x, Xh);
        hipLaunchKernelGGL(convert_wT,  dim3(DSAE/32, KD/64),   dim3(256), 0, stream, Wenc, Wt);
        hipLaunchKernelGGL(encode_gemm, dim3(DSAE/128, B_/128), dim3(256), 0, stream, Xh, Wt, benc, pre);
    } else {
        hipLaunchKernelGGL(encode_mfma, dim3(DSAE/128, B_/128), dim3(256), 0, stream, x, Wenc, benc, pre);
    }

    hipLaunchKernelGGL(select_topk, dim3(B_), dim3(256), 0, stream, pre, x, Wenc,
                       fast ? Wt : (const ushort*)nullptr, widx_g, wval_g,
                       fast ? 5e-3f : 2e-3f);
    hipLaunchKernelGGL(decode_loss, dim3(B_), dim3(256), 0, stream, widx_g, wval_g, Wdec, bdec, x, xhat, acc);
    hipLaunchKernelGGL(finalize,    dim3(1),  dim3(1),   0, stream, acc, out);
}

// Round 3
// 426.373 us; speedup vs baseline: 1.5747x; 1.0548x over previous
//
#include <hip/hip_runtime.h>
#include <hip/hip_fp16.h>
#include <cfloat>

#define B_    1024
#define T_    4
#define DIN   768
#define KD    3072      // T_*DIN, contracted dim of encoder
#define DSAE  8192
#define TOPK  32

static constexpr size_t XHAT_OFF = 1;
static constexpr size_t Z_OFF    = 1 + (size_t)B_ * T_ * DIN;   // 3145729

typedef __attribute__((ext_vector_type(8))) short    frag;    // 8 bf16 = 4 VGPRs (legacy path)
typedef __attribute__((ext_vector_type(8))) _Float16 hfrag;   // 8 fp16 = 4 VGPRs
typedef __attribute__((ext_vector_type(4))) float    f32x4;   // MFMA C/D

__device__ __forceinline__ unsigned pack2(float a, float b) {
    return (__builtin_bit_cast(unsigned, a) >> 16) | (__builtin_bit_cast(unsigned, b) & 0xFFFF0000u);
}
__device__ __forceinline__ float hi_part(float a) {
    return __builtin_bit_cast(float, __builtin_bit_cast(unsigned, a) & 0xFFFF0000u);
}

// ---------------------------------------------------------------- K0
__global__ void zero_acc(double* acc) { if (threadIdx.x == 0) *acc = 0.0; }

// ---------------------------------------------------------------- FAST PATH: convert kernels
__global__ __launch_bounds__(256) void convert_x(const float* __restrict__ x, ushort* __restrict__ Xh)
{
    const int row = blockIdx.y;
    const int col = blockIdx.x * 1024 + threadIdx.x * 4;
    const float4 f = *(const float4*)(x + (size_t)row * KD + col);
    ushort4 h;
    h.x = __half_as_ushort(__float2half(f.x));
    h.y = __half_as_ushort(__float2half(f.y));
    h.z = __half_as_ushort(__float2half(f.z));
    h.w = __half_as_ushort(__float2half(f.w));
    *(ushort4*)(Xh + (size_t)row * KD + col) = h;
}

// Wt[n][0..3071]    = fp16(W[k][n])                 (transposed hi — read by GEMM)
// Wt[n][3072..6143] = fp16((W[k][n]-hi)*2048)       (scaled residual — read only by the
//                                                    rare exact tie-break path in select_topk)
__global__ __launch_bounds__(256) void convert_wT(const float* __restrict__ W, ushort* __restrict__ Wt)
{
    __shared__ float t[64][33];
    const int tx = threadIdx.x & 31, ty = threadIdx.x >> 5;
    const int n0 = blockIdx.x * 32, k0 = blockIdx.y * 64;
    #pragma unroll
    for (int j = 0; j < 8; j++)
        t[ty + j * 8][tx] = W[(size_t)(k0 + ty + j * 8) * DSAE + n0 + tx];
    __syncthreads();
    #pragma unroll
    for (int j = 0; j < 4; j++) {
        const int nl = ty + j * 8;
        const float a = t[tx * 2][nl], b = t[tx * 2 + 1][nl];
        const __half ha = __float2half(a), hb = __float2half(b);
        const float ra = (a - __half2float(ha)) * 2048.0f;
        const float rb = (b - __half2float(hb)) * 2048.0f;
        const ushort2 hv = make_ushort2(__half_as_ushort(ha), __half_as_ushort(hb));
        const ushort2 lv = make_ushort2(__half_as_ushort(__float2half(ra)),
                                        __half_as_ushort(__float2half(rb)));
        ushort* dst = Wt + (size_t)(n0 + nl) * (2 * KD) + k0 + tx * 2;
        *(ushort2*)dst        = hv;
        *(ushort2*)(dst + KD) = lv;
    }
}

// ---------------------------------------------------------------- FAST PATH: single-product fp16 MFMA GEMM
// pre ~= Xh*Wh  (sigma err ~8e-4, max ~4.5e-3 over 8.4M atoms) — selection margin 1.25e-2
// covers 2x max err; exact tie-break path resolves the window. Halves MFMA work vs the
// 2-product version that measured 859 TF (structure ceiling).
__device__ __forceinline__ void gload16(const ushort* g, ushort* l)
{
    __builtin_amdgcn_global_load_lds((const __attribute__((address_space(1))) void*)g,
                                     (__attribute__((address_space(3))) void*)l, 16, 0, 0);
}

__global__ __launch_bounds__(256, 3) void encode_gemm(const ushort* __restrict__ Xh,
                                                      const ushort* __restrict__ Wt,
                                                      const float* __restrict__ benc,
                                                      float* __restrict__ pre)
{
    __shared__ ushort As [128 * 32];   // [m][k] 8 KB
    __shared__ ushort Bhs[128 * 32];   // [n][k] hi 8 KB

    const int tid  = threadIdx.x;
    const int n0   = blockIdx.x * 128, m0 = blockIdx.y * 128;
    const int lane = tid & 63, wv = tid >> 6;
    const int wrow = (wv >> 1) * 64, wcol = (wv & 1) * 64;
    const int lm = lane & 15, q = lane >> 4;

    f32x4 acc[4][4];
    #pragma unroll
    for (int i = 0; i < 4; i++)
        #pragma unroll
        for (int j = 0; j < 4; j++) acc[i][j] = (f32x4){0.f,0.f,0.f,0.f};

    // staging: per wave 1 KB/call = 16 rows x 64 B; lane l -> row l>>2, 16B-chunk l&3
    const int srow = lane >> 2, scol = (lane & 3) * 8;
    const ushort* pa0 = Xh + (size_t)(m0 + wv * 16 + srow) * KD + scol;
    const ushort* pa1 = pa0 + (size_t)64 * KD;
    const ushort* pb0 = Wt + (size_t)(n0 + wv * 16 + srow) * (2 * KD) + scol;
    const ushort* pb1 = pb0 + (size_t)64 * (2 * KD);
    ushort* da0 = &As [wv * 512]; ushort* da1 = &As [2048 + wv * 512];
    ushort* dh0 = &Bhs[wv * 512]; ushort* dh1 = &Bhs[2048 + wv * 512];

    for (int k0 = 0; k0 < KD; k0 += 32) {
        gload16(pa0 + k0, da0);
        gload16(pa1 + k0, da1);
        gload16(pb0 + k0, dh0);
        gload16(pb1 + k0, dh1);
        __syncthreads();

        hfrag af[4], bh[4];
        #pragma unroll
        for (int t4 = 0; t4 < 4; t4++) {
            af[t4] = *(const hfrag*)&As [(wrow + t4 * 16 + lm) * 32 + q * 8];
            bh[t4] = *(const hfrag*)&Bhs[(wcol + t4 * 16 + lm) * 32 + q * 8];
        }
        #pragma unroll
        for (int mt = 0; mt < 4; mt++)
            #pragma unroll
            for (int nt = 0; nt < 4; nt++)
                acc[mt][nt] = __builtin_amdgcn_mfma_f32_16x16x32_f16(af[mt], bh[nt], acc[mt][nt], 0, 0, 0);
        __syncthreads();
    }

    // epilogue: C/D layout col=lane&15, row=q*4+reg (verified)
    #pragma unroll
    for (int mt = 0; mt < 4; mt++)
        #pragma unroll
        for (int nt = 0; nt < 4; nt++) {
            const int col = n0 + wcol + nt * 16 + lm;
            const float bv = benc[col];
            #pragma unroll
            for (int r = 0; r < 4; r++) {
                const int row = m0 + wrow + mt * 16 + q * 4 + r;
                pre[(size_t)row * DSAE + col] = acc[mt][nt][r] + bv;
            }
        }
}

// ---------------------------------------------------------------- FALLBACK: bf16x2-split MFMA GEMM (unchanged)
#define PK 40
__global__ __launch_bounds__(256, 2) void encode_mfma(const float* __restrict__ x,
                                                      const float* __restrict__ W,
                                                      const float* __restrict__ benc,
                                                      float* __restrict__ pre)
{
    __shared__ short Ahi[128 * PK], Alo[128 * PK];
    __shared__ short Bhi[128 * PK], Blo[128 * PK];

    const int tid  = threadIdx.x;
    const int m0   = blockIdx.y * 128, n0 = blockIdx.x * 128;
    const int am = tid >> 1, ak = (tid & 1) << 4;
    const int bn = (tid & 31) << 2, bk = tid >> 5;
    const int lane = tid & 63, wv = tid >> 6;
    const int wrow = (wv >> 1) * 64, wcol = (wv & 1) * 64;
    const int lm = lane & 15, q = lane >> 4;

    f32x4 acc[4][4];
    #pragma unroll
    for (int i = 0; i < 4; i++)
        #pragma unroll
        for (int j = 0; j < 4; j++) acc[i][j] = (f32x4){0.f, 0.f, 0.f, 0.f};

    const float* pA0 = x + (size_t)(m0 + am) * KD + ak;
    const float* pB0 = W + (size_t)bk * 4 * DSAE + n0 + bn;

    for (int k0 = 0; k0 < KD; k0 += 32) {
        {
            const float* pA = pA0 + k0;
            float f[16];
            *(float4*)&f[0]  = *(const float4*)(pA);
            *(float4*)&f[4]  = *(const float4*)(pA + 4);
            *(float4*)&f[8]  = *(const float4*)(pA + 8);
            *(float4*)&f[12] = *(const float4*)(pA + 12);
            unsigned hw[8], lw[8];
            #pragma unroll
            for (int j = 0; j < 8; j++) {
                float a = f[2*j], b = f[2*j+1];
                float ha = hi_part(a), hb = hi_part(b);
                hw[j] = pack2(ha, hb);
                lw[j] = pack2(a - ha, b - hb);
            }
            short* dh = &Ahi[am * PK + ak];
            short* dl = &Alo[am * PK + ak];
            *(int4*)dh       = *(int4*)&hw[0];
            *(int4*)(dh + 8) = *(int4*)&hw[4];
            *(int4*)dl       = *(int4*)&lw[0];
            *(int4*)(dl + 8) = *(int4*)&lw[4];
        }
        {
            const float* pB = pB0 + (size_t)k0 * DSAE;
            float4 w0 = *(const float4*)(pB);
            float4 w1 = *(const float4*)(pB + DSAE);
            float4 w2 = *(const float4*)(pB + 2 * DSAE);
            float4 w3 = *(const float4*)(pB + 3 * DSAE);
            float fr[4][4] = {{w0.x,w0.y,w0.z,w0.w},{w1.x,w1.y,w1.z,w1.w},
                              {w2.x,w2.y,w2.z,w2.w},{w3.x,w3.y,w3.z,w3.w}};
            #pragma unroll
            for (int c = 0; c < 4; c++) {
                float h0 = hi_part(fr[0][c]), h1 = hi_part(fr[1][c]);
                float h2 = hi_part(fr[2][c]), h3 = hi_part(fr[3][c]);
                unsigned hh[2] = { pack2(h0, h1), pack2(h2, h3) };
                unsigned ll[2] = { pack2(fr[0][c]-h0, fr[1][c]-h1), pack2(fr[2][c]-h2, fr[3][c]-h3) };
                *(int2*)&Bhi[(bn + c) * PK + bk * 4] = *(int2*)&hh[0];
                *(int2*)&Blo[(bn + c) * PK + bk * 4] = *(int2*)&ll[0];
            }
        }
        __syncthreads();

        frag ah[4], al[4], bh[4], bl[4];
        #pragma unroll
        for (int t4 = 0; t4 < 4; t4++) {
            int r = (wrow + t4 * 16 + lm) * PK + q * 8;
            ah[t4] = *(const frag*)&Ahi[r];
            al[t4] = *(const frag*)&Alo[r];
            int cIdx = (wcol + t4 * 16 + lm) * PK + q * 8;
            bh[t4] = *(const frag*)&Bhi[cIdx];
            bl[t4] = *(const frag*)&Blo[cIdx];
        }
        #pragma unroll
        for (int mt = 0; mt < 4; mt++)
            #pragma unroll
            for (int nt = 0; nt < 4; nt++) {
                acc[mt][nt] = __builtin_amdgcn_mfma_f32_16x16x32_bf16(ah[mt], bh[nt], acc[mt][nt], 0, 0, 0);
                acc[mt][nt] = __builtin_amdgcn_mfma_f32_16x16x32_bf16(ah[mt], bl[nt], acc[mt][nt], 0, 0, 0);
                acc[mt][nt] = __builtin_amdgcn_mfma_f32_16x16x32_bf16(al[mt], bh[nt], acc[mt][nt], 0, 0, 0);
            }
        __syncthreads();
    }

    #pragma unroll
    for (int mt = 0; mt < 4; mt++)
        #pragma unroll
        for (int nt = 0; nt < 4; nt++) {
            int col = n0 + wcol + nt * 16 + lm;
            float bv = benc[col];
            #pragma unroll
            for (int r = 0; r < 4; r++) {
                int row = m0 + wrow + mt * 16 + q * 4 + r;
                pre[(size_t)row * DSAE + col] = acc[mt][nt][r] + bv;
            }
        }
}

// ---------------------------------------------------------------- K2: exact top-32 selection (candidate-prune)
__global__ __launch_bounds__(256) void select_topk(float* __restrict__ zout,
                                                   const float* __restrict__ x,
                                                   const float* __restrict__ W,
                                                   const ushort* __restrict__ Wt,  // fp16 hi/lo transposed copy (may be null)
                                                   int* __restrict__ widx_g,
                                                   float* __restrict__ wval_g,
                                                   float mgn)
{
    const int b   = blockIdx.x;
    const int tid = threadIdx.x;

    __shared__ float vals[DSAE];            // 32 KB
    __shared__ unsigned char flag[DSAE];    // 8 KB
    __shared__ float lmax[256];
    __shared__ float cand_v[512]; __shared__ int cand_i[512];   // 4 KB
    __shared__ float rv[256];  __shared__ int ri[256];
    __shared__ double dred[256];
    __shared__ float topv[TOPK]; __shared__ int topi[TOPK];
    __shared__ int wix[64]; __shared__ double wdv[64]; __shared__ unsigned char wsel[64];
    __shared__ int wcnt, nabove, outc, ncand;
    __shared__ float sL, sv32;

    float* zrow = zout + (size_t)b * DSAE;

    float lm = -FLT_MAX;
    #pragma unroll
    for (int p = 0; p < DSAE / 256; p++) {
        float v = zrow[tid + p * 256];
        vals[tid + p * 256] = v;
        lm = fmaxf(lm, v);
    }
    lmax[tid] = lm;
    if (tid == 0) { ncand = 0; wcnt = 0; nabove = 0; outc = 0; }
    __syncthreads();

    // rank this thread's max among the 256 (desc, index tiebreak) -> L = 32nd largest
    {
        int rk = 0;
        for (int j = 0; j < 256; j++) {
            float o = lmax[j];
            rk += (o > lm || (o == lm && j < tid)) ? 1 : 0;
        }
        if (rk == TOPK - 1) sL = lm;
    }
    __syncthreads();
    const float L = sL;

    for (int p = 0; p < DSAE / 256; p++) {
        int i = tid + p * 256;
        float v = vals[i];
        if (v > L) {
            int s = atomicAdd(&ncand, 1);
            if (s < 512) { cand_v[s] = v; cand_i[s] = i; }
        }
    }
    __syncthreads();
    const int ncg = ncand;

    if (ncg < TOPK) {
        if (tid == 0) sv32 = L;
    } else if (ncg <= 512) {
        for (int j = tid; j < ncg; j += 256) {
            float v = cand_v[j]; int idx = cand_i[j];
            int r = 0;
            for (int k2 = 0; k2 < ncg; k2++) {
                float o = cand_v[k2];
                r += (o > v || (o == v && cand_i[k2] < idx)) ? 1 : 0;
            }
            if (r == TOPK - 1) sv32 = v;
        }
    } else {
        // degenerate: original destructive 32-pass selection + restore
        for (int pass = 0; pass < TOPK; pass++) {
            float bv = -FLT_MAX; int bi = 0x7fffffff;
            for (int p = 0; p < DSAE / 256; p++) {
                int i = tid + p * 256;
                float v = vals[i];
                if (v > bv) { bv = v; bi = i; }
            }
            rv[tid] = bv; ri[tid] = bi; __syncthreads();
            for (int s = 128; s > 0; s >>= 1) {
                if (tid < s) {
                    if (rv[tid + s] > rv[tid] || (rv[tid + s] == rv[tid] && ri[tid + s] < ri[tid])) {
                        rv[tid] = rv[tid + s]; ri[tid] = ri[tid + s];
                    }
                }
                __syncthreads();
            }
            if (tid == 0) { topv[pass] = rv[0]; topi[pass] = ri[0]; vals[ri[0]] = -FLT_MAX; }
            __syncthreads();
        }
        if (tid < TOPK) vals[topi[tid]] = topv[tid];
        if (tid == 0) sv32 = topv[TOPK - 1];
    }
    __syncthreads();
    const float v32 = sv32;

    for (int p = 0; p < DSAE / 256; p++) {
        int i = tid + p * 256;
        float v = vals[i];
        if (v > v32 + mgn) { atomicAdd(&nabove, 1); }
        else if (v >= v32 - mgn) { int slot = atomicAdd(&wcnt, 1); if (slot < 64) wix[slot] = i; }
    }
    __syncthreads();
    const int nw   = wcnt < 64 ? wcnt : 64;
    const int need = TOPK - nabove;

    if (nw == need) {
        if (tid < 64) wsel[tid] = (tid < nw) ? 1 : 0;
    } else {
        // high-precision re-computation of window atoms (Wt hi+lo: err ~5e-7, coalesced)
        const float* xr = x + (size_t)b * KD;
        for (int w = 0; w < nw; w++) {
            const int s = wix[w];
            double part = 0.0;
            if (Wt) {
                const ushort* wr = Wt + (size_t)s * (2 * KD);
                for (int kk = tid; kk < KD; kk += 256) {
                    double wvd = (double)__half2float(__ushort_as_half(wr[kk]))
                               + (double)__half2float(__ushort_as_half(wr[kk + KD])) * (1.0 / 2048.0);
                    part += (double)xr[kk] * wvd;
                }
            } else {
                for (int kk = tid; kk < KD; kk += 256)
                    part += (double)xr[kk] * (double)W[(size_t)kk * DSAE + s];
            }
            dred[tid] = part; __syncthreads();
            for (int st = 128; st > 0; st >>= 1) { if (tid < st) dred[tid] += dred[tid + st]; __syncthreads(); }
            if (tid == 0) wdv[w] = dred[0];
            __syncthreads();
        }
        if (tid < 64) {
            unsigned char sel = 0;
            if (tid < nw) {
                int rank = 0;
                double mv = wdv[tid]; int mi = wix[tid];
                for (int w2 = 0; w2 < nw; w2++)
                    if (wdv[w2] > mv || (wdv[w2] == mv && wix[w2] < mi)) rank++;
                sel = (rank < need) ? 1 : 0;
            }
            wsel[tid] = sel;
        }
    }
    __syncthreads();

    for (int p = 0; p < DSAE / 256; p++) flag[tid + p * 256] = 0;
    __syncthreads();
    for (int p = 0; p < DSAE / 256; p++) {
        int i = tid + p * 256;
        if (vals[i] > v32 + mgn) flag[i] = 1;
    }
    if (tid < nw && wsel[tid]) flag[wix[tid]] = 1;
    __syncthreads();

    for (int p = 0; p < DSAE / 256; p++) {
        int i = tid + p * 256;
        float v = vals[i];
        float zv = 0.f;
        if (flag[i]) {
            zv = v > 0.f ? v : 0.f;
            int slot = atomicAdd(&outc, 1);
            if (slot < TOPK) { widx_g[b * TOPK + slot] = i; wval_g[b * TOPK + slot] = zv; }
        }
        zrow[i] = zv;
    }
}

// ---------------------------------------------------------------- K3: sparse decode + fused loss (float4 + 2-stage prefetch)
__global__ __launch_bounds__(256) void decode_loss(const int* __restrict__ widx_g,
                                                   const float* __restrict__ wval_g,
                                                   const float* __restrict__ Wdec,
                                                   const float* __restrict__ bdec,
                                                   const float* __restrict__ x,
                                                   float* __restrict__ xhat,
                                                   double* __restrict__ acc)
{
    const int b = blockIdx.x, tid = threadIdx.x;
    __shared__ int sidx[TOPK]; __shared__ float sval[TOPK];
    __shared__ double dred[256];
    if (tid < TOPK) { sidx[tid] = widx_g[b * TOPK + tid]; sval[tid] = wval_g[b * TOPK + tid]; }
    __syncthreads();

    float4 o[3];
    #pragma unroll
    for (int c = 0; c < 3; c++) o[c] = ((const float4*)bdec)[tid + c * 256];

    // 2-stage pipeline: issue next row's loads before this row's fma chain
    float4 wn[3];
    {
        const float4* wr = (const float4*)(Wdec + (size_t)sidx[0] * KD);
        #pragma unroll
        for (int c = 0; c < 3; c++) wn[c] = wr[tid + c * 256];
    }
    for (int j = 0; j < TOPK; j++) {
        const float v = sval[j];
        float4 w[3];
        #pragma unroll
        for (int c = 0; c < 3; c++) w[c] = wn[c];
        if (j + 1 < TOPK) {
            const float4* wr = (const float4*)(Wdec + (size_t)sidx[j + 1] * KD);
            #pragma unroll
            for (int c = 0; c < 3; c++) wn[c] = wr[tid + c * 256];
        }
        #pragma unroll
        for (int c = 0; c < 3; c++) {
            o[c].x = fmaf(v, w[c].x, o[c].x);
            o[c].y = fmaf(v, w[c].y, o[c].y);
            o[c].z = fmaf(v, w[c].z, o[c].z);
            o[c].w = fmaf(v, w[c].w, o[c].w);
        }
    }

    double ls = 0.0;
    const float4* xr = (const float4*)(x + (size_t)b * KD);
    float* xo = xhat + (size_t)b * KD;     // offset 4 mod 16 -> scalar stores
    #pragma unroll
    for (int c = 0; c < 3; c++) {
        float4 xv = xr[tid + c * 256];
        float4 ov = o[c];
        float d0 = ov.x - xv.x, d1 = ov.y - xv.y, d2 = ov.z - xv.z, d3 = ov.w - xv.w;
        ls += (double)d0 * (double)d0 + (double)d1 * (double)d1
            + (double)d2 * (double)d2 + (double)d3 * (double)d3;
        const int e = (tid + c * 256) * 4;
        xo[e] = ov.x; xo[e + 1] = ov.y; xo[e + 2] = ov.z; xo[e + 3] = ov.w;
    }
    dred[tid] = ls; __syncthreads();
    for (int s = 128; s > 0; s >>= 1) { if (tid < s) dred[tid] += dred[tid + s]; __syncthreads(); }
    if (tid == 0) atomicAdd(acc, dred[0]);
}

// ---------------------------------------------------------------- K4: finalize
__global__ void finalize(const double* __restrict__ acc, float* __restrict__ out)
{
    if (threadIdx.x == 0) out[0] = (float)(*acc / (double)(B_ * T_));
}

// ----------------------------------------------------------------
extern "C" void kernel_launch(void* const* d_in, const int* in_sizes, int n_in,
                              void* d_out, int out_size, void* d_ws, size_t ws_size,
                              hipStream_t stream)
{
    (void)in_sizes; (void)n_in; (void)out_size;
    const float* x    = (const float*)d_in[0];
    const float* Wenc = (const float*)d_in[1];
    const float* Wdec = (const float*)d_in[2];
    const float* benc = (const float*)d_in[3];
    const float* bdec = (const float*)d_in[4];

    float*  out    = (float*)d_out;
    double* acc    = (double*)d_ws;
    int*    widx_g = (int*)((char*)d_ws + 16);
    float*  wval_g = (float*)((char*)d_ws + 16 + (size_t)B_ * TOPK * 4);

    // fast-path workspace layout
    const size_t XC_OFF = (size_t)1 << 20;                       // Xh: 1024*3072*2  = 6.3 MB
    const size_t WT_OFF = (size_t)8 << 20;                       // Wt: 8192*6144*2  = 100.7 MB
    const size_t NEED   = WT_OFF + (size_t)DSAE * (2 * KD) * 2;  // ~109 MB
    const bool fast = (ws_size >= NEED);

    float* pre  = out + Z_OFF;     // z region doubles as the dense pre buffer
    float* xhat = out + XHAT_OFF;

    hipLaunchKernelGGL(zero_acc, dim3(1), dim3(1), 0, stream, acc);

    ushort* Xh = (ushort*)((char*)d_ws + XC_OFF);
    ushort* Wt = (ushort*)((char*)d_ws + WT_OFF);
    if (fast) {
        hipLaunchKernelGGL(convert_x,   dim3(3, B_),            dim3(256), 0, stream, x, Xh);
        hipLaunchKernelGGL(convert_wT,  dim3(DSAE/32, KD/64),   dim3(256), 0, stream, Wenc, Wt);
        hipLaunchKernelGGL(encode_gemm, dim3(DSAE/128, B_/128), dim3(256), 0, stream, Xh, Wt, benc, pre);
    } else {
        hipLaunchKernelGGL(encode_mfma, dim3(DSAE/128, B_/128), dim3(256), 0, stream, x, Wenc, benc, pre);
    }

    // margin: single-fp16-product GEMM max err ~4.5e-3 -> mgn must exceed 2x that
    hipLaunchKernelGGL(select_topk, dim3(B_), dim3(256), 0, stream, pre, x, Wenc,
                       fast ? Wt : (const ushort*)nullptr, widx_g, wval_g,
                       fast ? 1.25e-2f : 2e-3f);
    hipLaunchKernelGGL(decode_loss, dim3(B_), dim3(256), 0, stream, widx_g, wval_g, Wdec, bdec, x, xhat, acc);
    hipLaunchKernelGGL(finalize,    dim3(1),  dim3(1),   0, stream, acc, out);
}

// Round 5
// 420.506 us; speedup vs baseline: 1.5967x; 1.0140x over previous
//
#include <hip/hip_runtime.h>
#include <hip/hip_fp16.h>
#include <cfloat>

#define B_    1024
#define T_    4
#define DIN   768
#define KD    3072      // T_*DIN, contracted dim of encoder
#define DSAE  8192
#define TOPK  32

static constexpr size_t XHAT_OFF = 1;
static constexpr size_t Z_OFF    = 1 + (size_t)B_ * T_ * DIN;   // 3145729

typedef __attribute__((ext_vector_type(8))) short    frag;    // 8 bf16 = 4 VGPRs (legacy path)
typedef __attribute__((ext_vector_type(8))) _Float16 hfrag;   // 8 fp16 = 4 VGPRs
typedef __attribute__((ext_vector_type(4))) float    f32x4;   // MFMA C/D

__device__ __forceinline__ unsigned pack2(float a, float b) {
    return (__builtin_bit_cast(unsigned, a) >> 16) | (__builtin_bit_cast(unsigned, b) & 0xFFFF0000u);
}
__device__ __forceinline__ float hi_part(float a) {
    return __builtin_bit_cast(float, __builtin_bit_cast(unsigned, a) & 0xFFFF0000u);
}

// ---------------------------------------------------------------- K0 (legacy tier only)
__global__ void zero_acc(double* acc) { if (threadIdx.x == 0) *acc = 0.0; }

// ---------------------------------------------------------------- FAST PATH: convert kernels
// Also zeroes the loss accumulator (fuses zero_acc).
__global__ __launch_bounds__(256) void convert_x(const float* __restrict__ x, ushort* __restrict__ Xh,
                                                 double* __restrict__ acc)
{
    if (blockIdx.x == 0 && blockIdx.y == 0 && threadIdx.x == 0) *acc = 0.0;
    const int row = blockIdx.y;
    const int col = blockIdx.x * 1024 + threadIdx.x * 4;
    const float4 f = *(const float4*)(x + (size_t)row * KD + col);
    ushort4 h;
    h.x = __half_as_ushort(__float2half(f.x));
    h.y = __half_as_ushort(__float2half(f.y));
    h.z = __half_as_ushort(__float2half(f.z));
    h.w = __half_as_ushort(__float2half(f.w));
    *(ushort4*)(Xh + (size_t)row * KD + col) = h;
}

// Wt[n][0..3071]    = fp16(W[k][n])              (transposed hi — read by GEMM)
// Wt[n][3072..6143] = fp16((W[k][n]-hi)*2048)    (scaled residual — tie-break path only)
__global__ __launch_bounds__(256) void convert_wT(const float* __restrict__ W, ushort* __restrict__ Wt)
{
    __shared__ float t[64][33];
    const int tx = threadIdx.x & 31, ty = threadIdx.x >> 5;
    const int n0 = blockIdx.x * 32, k0 = blockIdx.y * 64;
    #pragma unroll
    for (int j = 0; j < 8; j++)
        t[ty + j * 8][tx] = W[(size_t)(k0 + ty + j * 8) * DSAE + n0 + tx];
    __syncthreads();
    #pragma unroll
    for (int j = 0; j < 4; j++) {
        const int nl = ty + j * 8;
        const float a = t[tx * 2][nl], b = t[tx * 2 + 1][nl];
        const __half ha = __float2half(a), hb = __float2half(b);
        const float ra = (a - __half2float(ha)) * 2048.0f;
        const float rb = (b - __half2float(hb)) * 2048.0f;
        const ushort2 hv = make_ushort2(__half_as_ushort(ha), __half_as_ushort(hb));
        const ushort2 lv = make_ushort2(__half_as_ushort(__float2half(ra)),
                                        __half_as_ushort(__float2half(rb)));
        ushort* dst = Wt + (size_t)(n0 + nl) * (2 * KD) + k0 + tx * 2;
        *(ushort2*)dst        = hv;
        *(ushort2*)(dst + KD) = lv;
    }
}

// ---------------------------------------------------------------- FAST PATH: single-product fp16 MFMA GEMM
__device__ __forceinline__ void gload16(const ushort* g, ushort* l)
{
    __builtin_amdgcn_global_load_lds((const __attribute__((address_space(1))) void*)g,
                                     (__attribute__((address_space(3))) void*)l, 16, 0, 0);
}

__global__ __launch_bounds__(256, 3) void encode_gemm(const ushort* __restrict__ Xh,
                                                      const ushort* __restrict__ Wt,
                                                      const float* __restrict__ benc,
                                                      float* __restrict__ pre)
{
    __shared__ ushort As [128 * 32];   // [m][k] 8 KB
    __shared__ ushort Bhs[128 * 32];   // [n][k] hi 8 KB

    const int tid  = threadIdx.x;
    const int n0   = blockIdx.x * 128, m0 = blockIdx.y * 128;
    const int lane = tid & 63, wv = tid >> 6;
    const int wrow = (wv >> 1) * 64, wcol = (wv & 1) * 64;
    const int lm = lane & 15, q = lane >> 4;

    f32x4 acc[4][4];
    #pragma unroll
    for (int i = 0; i < 4; i++)
        #pragma unroll
        for (int j = 0; j < 4; j++) acc[i][j] = (f32x4){0.f,0.f,0.f,0.f};

    const int srow = lane >> 2, scol = (lane & 3) * 8;
    const ushort* pa0 = Xh + (size_t)(m0 + wv * 16 + srow) * KD + scol;
    const ushort* pa1 = pa0 + (size_t)64 * KD;
    const ushort* pb0 = Wt + (size_t)(n0 + wv * 16 + srow) * (2 * KD) + scol;
    const ushort* pb1 = pb0 + (size_t)64 * (2 * KD);
    ushort* da0 = &As [wv * 512]; ushort* da1 = &As [2048 + wv * 512];
    ushort* dh0 = &Bhs[wv * 512]; ushort* dh1 = &Bhs[2048 + wv * 512];

    for (int k0 = 0; k0 < KD; k0 += 32) {
        gload16(pa0 + k0, da0);
        gload16(pa1 + k0, da1);
        gload16(pb0 + k0, dh0);
        gload16(pb1 + k0, dh1);
        __syncthreads();

        hfrag af[4], bh[4];
        #pragma unroll
        for (int t4 = 0; t4 < 4; t4++) {
            af[t4] = *(const hfrag*)&As [(wrow + t4 * 16 + lm) * 32 + q * 8];
            bh[t4] = *(const hfrag*)&Bhs[(wcol + t4 * 16 + lm) * 32 + q * 8];
        }
        #pragma unroll
        for (int mt = 0; mt < 4; mt++)
            #pragma unroll
            for (int nt = 0; nt < 4; nt++)
                acc[mt][nt] = __builtin_amdgcn_mfma_f32_16x16x32_f16(af[mt], bh[nt], acc[mt][nt], 0, 0, 0);
        __syncthreads();
    }

    #pragma unroll
    for (int mt = 0; mt < 4; mt++)
        #pragma unroll
        for (int nt = 0; nt < 4; nt++) {
            const int col = n0 + wcol + nt * 16 + lm;
            const float bv = benc[col];
            #pragma unroll
            for (int r = 0; r < 4; r++) {
                const int row = m0 + wrow + mt * 16 + q * 4 + r;
                pre[(size_t)row * DSAE + col] = acc[mt][nt][r] + bv;
            }
        }
}

// ---------------------------------------------------------------- FALLBACK: bf16x2-split MFMA GEMM (unchanged)
#define PK 40
__global__ __launch_bounds__(256, 2) void encode_mfma(const float* __restrict__ x,
                                                      const float* __restrict__ W,
                                                      const float* __restrict__ benc,
                                                      float* __restrict__ pre)
{
    __shared__ short Ahi[128 * PK], Alo[128 * PK];
    __shared__ short Bhi[128 * PK], Blo[128 * PK];

    const int tid  = threadIdx.x;
    const int m0   = blockIdx.y * 128, n0 = blockIdx.x * 128;
    const int am = tid >> 1, ak = (tid & 1) << 4;
    const int bn = (tid & 31) << 2, bk = tid >> 5;
    const int lane = tid & 63, wv = tid >> 6;
    const int wrow = (wv >> 1) * 64, wcol = (wv & 1) * 64;
    const int lm = lane & 15, q = lane >> 4;

    f32x4 acc[4][4];
    #pragma unroll
    for (int i = 0; i < 4; i++)
        #pragma unroll
        for (int j = 0; j < 4; j++) acc[i][j] = (f32x4){0.f, 0.f, 0.f, 0.f};

    const float* pA0 = x + (size_t)(m0 + am) * KD + ak;
    const float* pB0 = W + (size_t)bk * 4 * DSAE + n0 + bn;

    for (int k0 = 0; k0 < KD; k0 += 32) {
        {
            const float* pA = pA0 + k0;
            float f[16];
            *(float4*)&f[0]  = *(const float4*)(pA);
            *(float4*)&f[4]  = *(const float4*)(pA + 4);
            *(float4*)&f[8]  = *(const float4*)(pA + 8);
            *(float4*)&f[12] = *(const float4*)(pA + 12);
            unsigned hw[8], lw[8];
            #pragma unroll
            for (int j = 0; j < 8; j++) {
                float a = f[2*j], b = f[2*j+1];
                float ha = hi_part(a), hb = hi_part(b);
                hw[j] = pack2(ha, hb);
                lw[j] = pack2(a - ha, b - hb);
            }
            short* dh = &Ahi[am * PK + ak];
            short* dl = &Alo[am * PK + ak];
            *(int4*)dh       = *(int4*)&hw[0];
            *(int4*)(dh + 8) = *(int4*)&hw[4];
            *(int4*)dl       = *(int4*)&lw[0];
            *(int4*)(dl + 8) = *(int4*)&lw[4];
        }
        {
            const float* pB = pB0 + (size_t)k0 * DSAE;
            float4 w0 = *(const float4*)(pB);
            float4 w1 = *(const float4*)(pB + DSAE);
            float4 w2 = *(const float4*)(pB + 2 * DSAE);
            float4 w3 = *(const float4*)(pB + 3 * DSAE);
            float fr[4][4] = {{w0.x,w0.y,w0.z,w0.w},{w1.x,w1.y,w1.z,w1.w},
                              {w2.x,w2.y,w2.z,w2.w},{w3.x,w3.y,w3.z,w3.w}};
            #pragma unroll
            for (int c = 0; c < 4; c++) {
                float h0 = hi_part(fr[0][c]), h1 = hi_part(fr[1][c]);
                float h2 = hi_part(fr[2][c]), h3 = hi_part(fr[3][c]);
                unsigned hh[2] = { pack2(h0, h1), pack2(h2, h3) };
                unsigned ll[2] = { pack2(fr[0][c]-h0, fr[1][c]-h1), pack2(fr[2][c]-h2, fr[3][c]-h3) };
                *(int2*)&Bhi[(bn + c) * PK + bk * 4] = *(int2*)&hh[0];
                *(int2*)&Blo[(bn + c) * PK + bk * 4] = *(int2*)&ll[0];
            }
        }
        __syncthreads();

        frag ah[4], al[4], bh[4], bl[4];
        #pragma unroll
        for (int t4 = 0; t4 < 4; t4++) {
            int r = (wrow + t4 * 16 + lm) * PK + q * 8;
            ah[t4] = *(const frag*)&Ahi[r];
            al[t4] = *(const frag*)&Alo[r];
            int cIdx = (wcol + t4 * 16 + lm) * PK + q * 8;
            bh[t4] = *(const frag*)&Bhi[cIdx];
            bl[t4] = *(const frag*)&Blo[cIdx];
        }
        #pragma unroll
        for (int mt = 0; mt < 4; mt++)
            #pragma unroll
            for (int nt = 0; nt < 4; nt++) {
                acc[mt][nt] = __builtin_amdgcn_mfma_f32_16x16x32_bf16(ah[mt], bh[nt], acc[mt][nt], 0, 0, 0);
                acc[mt][nt] = __builtin_amdgcn_mfma_f32_16x16x32_bf16(ah[mt], bl[nt], acc[mt][nt], 0, 0, 0);
                acc[mt][nt] = __builtin_amdgcn_mfma_f32_16x16x32_bf16(al[mt], bh[nt], acc[mt][nt], 0, 0, 0);
            }
        __syncthreads();
    }

    #pragma unroll
    for (int mt = 0; mt < 4; mt++)
        #pragma unroll
        for (int nt = 0; nt < 4; nt++) {
            int col = n0 + wcol + nt * 16 + lm;
            float bv = benc[col];
            #pragma unroll
            for (int r = 0; r < 4; r++) {
                int row = m0 + wrow + mt * 16 + q * 4 + r;
                pre[(size_t)row * DSAE + col] = acc[mt][nt][r] + bv;
            }
        }
}

// ---------------------------------------------------------------- K2-FAST: register-resident top-32 selection
__global__ __launch_bounds__(256) void select_topk_fast(const float* __restrict__ pre,
                                                        float* __restrict__ zout,
                                                        const float* __restrict__ x,
                                                        const ushort* __restrict__ Wt,
                                                        int* __restrict__ widx_g,
                                                        float* __restrict__ wval_g,
                                                        float mgn)
{
    const int b = blockIdx.x, tid = threadIdx.x;

    __shared__ float lmax[256];
    __shared__ float cand_v[512]; __shared__ int cand_i[512];
    __shared__ float rv[256]; __shared__ int ri[256];
    __shared__ int wix[64]; __shared__ double wdv[64]; __shared__ unsigned char wsel[64];
    __shared__ int selix[64];
    __shared__ int wcnt, nabove, outc, ncand, nsel;
    __shared__ float sL, sv32;

    const float4* pre4 = (const float4*)(pre + (size_t)b * DSAE);
    float4 r[8];
    float lm = -FLT_MAX;
    #pragma unroll
    for (int p = 0; p < 8; p++) {
        r[p] = pre4[p * 256 + tid];
        lm = fmaxf(fmaxf(fmaxf(lm, r[p].x), fmaxf(r[p].y, r[p].z)), r[p].w);
    }
    lmax[tid] = lm;
    if (tid == 0) { ncand = 0; wcnt = 0; nabove = 0; outc = 0; nsel = 0; }
    __syncthreads();

    // L = 32nd-largest per-thread max (desc, idx tiebreak): provable lower bound on v32
    {
        int rk = 0;
        for (int j = 0; j < 256; j++) {
            float o = lmax[j];
            rk += (o > lm || (o == lm && j < tid)) ? 1 : 0;
        }
        if (rk == TOPK - 1) sL = lm;
    }
    __syncthreads();
    const float L = sL;

    // compact strict candidates v > L
    #pragma unroll
    for (int p = 0; p < 8; p++) {
        const int base = (p * 256 + tid) * 4;
        const float vv[4] = {r[p].x, r[p].y, r[p].z, r[p].w};
        #pragma unroll
        for (int c = 0; c < 4; c++)
            if (vv[c] > L) {
                int s = atomicAdd(&ncand, 1);
                if (s < 512) { cand_v[s] = vv[c]; cand_i[s] = base + c; }
            }
    }
    __syncthreads();
    const int ncg = ncand;

    if (ncg < TOPK) {
        if (tid == 0) sv32 = L;   // v32 == L exactly
    } else if (ncg <= 512) {
        for (int j = tid; j < ncg; j += 256) {
            float v = cand_v[j]; int idx = cand_i[j];
            int rr = 0;
            for (int k2 = 0; k2 < ncg; k2++) {
                float o = cand_v[k2];
                rr += (o > v || (o == v && cand_i[k2] < idx)) ? 1 : 0;
            }
            if (rr == TOPK - 1) sv32 = v;
        }
    } else {
        // degenerate (massive ties): destructive 32-pass over register copies
        unsigned tmask = 0;   // bit (p*4+c) == element taken
        for (int pass = 0; pass < TOPK; pass++) {
            float bv = -FLT_MAX; int bi = 0x7fffffff;
            #pragma unroll
            for (int p = 0; p < 8; p++) {
                const int base = (p * 256 + tid) * 4;
                const float vv[4] = {r[p].x, r[p].y, r[p].z, r[p].w};
                #pragma unroll
                for (int c = 0; c < 4; c++)
                    if (!((tmask >> (p * 4 + c)) & 1u) && vv[c] > bv) { bv = vv[c]; bi = base + c; }
            }
            rv[tid] = bv; ri[tid] = bi; __syncthreads();
            for (int s = 128; s > 0; s >>= 1) {
                if (tid < s) {
                    if (rv[tid + s] > rv[tid] || (rv[tid + s] == rv[tid] && ri[tid + s] < ri[tid])) {
                        rv[tid] = rv[tid + s]; ri[tid] = ri[tid + s];
                    }
                }
                __syncthreads();
            }
            const int gi = ri[0];
            if (tid == ((gi >> 2) & 255)) tmask |= 1u << (((gi >> 10) << 2) | (gi & 3));
            if (tid == 0 && pass == TOPK - 1) sv32 = rv[0];
            __syncthreads();
        }
    }
    __syncthreads();
    const float v32 = sv32;

    // margin window around v32
    #pragma unroll
    for (int p = 0; p < 8; p++) {
        const int base = (p * 256 + tid) * 4;
        const float vv[4] = {r[p].x, r[p].y, r[p].z, r[p].w};
        #pragma unroll
        for (int c = 0; c < 4; c++) {
            const float v = vv[c];
            if (v > v32 + mgn) { atomicAdd(&nabove, 1); }
            else if (v >= v32 - mgn) { int slot = atomicAdd(&wcnt, 1); if (slot < 64) wix[slot] = base + c; }
        }
    }
    __syncthreads();
    const int nw   = wcnt < 64 ? wcnt : 64;
    const int need = TOPK - nabove;

    if (nw == need) {
        if (tid < 64) wsel[tid] = (tid < nw) ? 1 : 0;
    } else {
        // wave-parallel high-precision recompute: one atom per wave, shuffle reduce
        const float* xr = x + (size_t)b * KD;
        const int wvId = tid >> 6, lane = tid & 63;
        for (int w = wvId; w < nw; w += 4) {
            const ushort* wr = Wt + (size_t)wix[w] * (2 * KD);
            double part = 0.0;
            for (int kk = lane; kk < KD; kk += 64) {
                double wvd = (double)__half2float(__ushort_as_half(wr[kk]))
                           + (double)__half2float(__ushort_as_half(wr[kk + KD])) * (1.0 / 2048.0);
                part += (double)xr[kk] * wvd;
            }
            #pragma unroll
            for (int off = 32; off > 0; off >>= 1) part += __shfl_down(part, off);
            if (lane == 0) wdv[w] = part;
        }
        __syncthreads();
        if (tid < 64) {
            unsigned char sel = 0;
            if (tid < nw) {
                int rank = 0;
                double mv = wdv[tid]; int mi = wix[tid];
                for (int w2 = 0; w2 < nw; w2++)
                    if (wdv[w2] > mv || (wdv[w2] == mv && wix[w2] < mi)) rank++;
                sel = (rank < need) ? 1 : 0;
            }
            wsel[tid] = sel;
        }
    }
    __syncthreads();

    // compact selected window indices (typically 1-3)
    if (tid < nw && wsel[tid]) { int s = atomicAdd(&nsel, 1); selix[s] = wix[tid]; }
    __syncthreads();
    const int ns = nsel;

    // final sweep: z write + top-k output
    float* zrow = zout + (size_t)b * DSAE;
    #pragma unroll
    for (int p = 0; p < 8; p++) {
        const int base = (p * 256 + tid) * 4;
        const float vv[4] = {r[p].x, r[p].y, r[p].z, r[p].w};
        #pragma unroll
        for (int c = 0; c < 4; c++) {
            const float v = vv[c];
            bool pick = (v > v32 + mgn);
            if (!pick && v >= v32 - mgn)
                for (int s2 = 0; s2 < ns; s2++) pick = pick || (selix[s2] == base + c);
            float zv = 0.f;
            if (pick) {
                zv = v > 0.f ? v : 0.f;
                int slot = atomicAdd(&outc, 1);
                if (slot < TOPK) { widx_g[b * TOPK + slot] = base + c; wval_g[b * TOPK + slot] = zv; }
            }
            zrow[base + c] = zv;
        }
    }
}

// ---------------------------------------------------------------- K2-LEGACY: in-place selection (MID/fallback tiers)
__global__ __launch_bounds__(256) void select_topk(float* __restrict__ zout,
                                                   const float* __restrict__ x,
                                                   const float* __restrict__ W,
                                                   const ushort* __restrict__ Wt,
                                                   int* __restrict__ widx_g,
                                                   float* __restrict__ wval_g,
                                                   float mgn)
{
    const int b   = blockIdx.x;
    const int tid = threadIdx.x;

    __shared__ float vals[DSAE];
    __shared__ unsigned char flag[DSAE];
    __shared__ float lmax[256];
    __shared__ float cand_v[512]; __shared__ int cand_i[512];
    __shared__ float rv[256];  __shared__ int ri[256];
    __shared__ double dred[256];
    __shared__ float topv[TOPK]; __shared__ int topi[TOPK];
    __shared__ int wix[64]; __shared__ double wdv[64]; __shared__ unsigned char wsel[64];
    __shared__ int wcnt, nabove, outc, ncand;
    __shared__ float sL, sv32;

    float* zrow = zout + (size_t)b * DSAE;

    float lm = -FLT_MAX;
    #pragma unroll
    for (int p = 0; p < DSAE / 256; p++) {
        float v = zrow[tid + p * 256];
        vals[tid + p * 256] = v;
        lm = fmaxf(lm, v);
    }
    lmax[tid] = lm;
    if (tid == 0) { ncand = 0; wcnt = 0; nabove = 0; outc = 0; }
    __syncthreads();

    {
        int rk = 0;
        for (int j = 0; j < 256; j++) {
            float o = lmax[j];
            rk += (o > lm || (o == lm && j < tid)) ? 1 : 0;
        }
        if (rk == TOPK - 1) sL = lm;
    }
    __syncthreads();
    const float L = sL;

    for (int p = 0; p < DSAE / 256; p++) {
        int i = tid + p * 256;
        float v = vals[i];
        if (v > L) {
            int s = atomicAdd(&ncand, 1);
            if (s < 512) { cand_v[s] = v; cand_i[s] = i; }
        }
    }
    __syncthreads();
    const int ncg = ncand;

    if (ncg < TOPK) {
        if (tid == 0) sv32 = L;
    } else if (ncg <= 512) {
        for (int j = tid; j < ncg; j += 256) {
            float v = cand_v[j]; int idx = cand_i[j];
            int r = 0;
            for (int k2 = 0; k2 < ncg; k2++) {
                float o = cand_v[k2];
                r += (o > v || (o == v && cand_i[k2] < idx)) ? 1 : 0;
            }
            if (r == TOPK - 1) sv32 = v;
        }
    } else {
        for (int pass = 0; pass < TOPK; pass++) {
            float bv = -FLT_MAX; int bi = 0x7fffffff;
            for (int p = 0; p < DSAE / 256; p++) {
                int i = tid + p * 256;
                float v = vals[i];
                if (v > bv) { bv = v; bi = i; }
            }
            rv[tid] = bv; ri[tid] = bi; __syncthreads();
            for (int s = 128; s > 0; s >>= 1) {
                if (tid < s) {
                    if (rv[tid + s] > rv[tid] || (rv[tid + s] == rv[tid] && ri[tid + s] < ri[tid])) {
                        rv[tid] = rv[tid + s]; ri[tid] = ri[tid + s];
                    }
                }
                __syncthreads();
            }
            if (tid == 0) { topv[pass] = rv[0]; topi[pass] = ri[0]; vals[ri[0]] = -FLT_MAX; }
            __syncthreads();
        }
        if (tid < TOPK) vals[topi[tid]] = topv[tid];
        if (tid == 0) sv32 = topv[TOPK - 1];
    }
    __syncthreads();
    const float v32 = sv32;

    for (int p = 0; p < DSAE / 256; p++) {
        int i = tid + p * 256;
        float v = vals[i];
        if (v > v32 + mgn) { atomicAdd(&nabove, 1); }
        else if (v >= v32 - mgn) { int slot = atomicAdd(&wcnt, 1); if (slot < 64) wix[slot] = i; }
    }
    __syncthreads();
    const int nw   = wcnt < 64 ? wcnt : 64;
    const int need = TOPK - nabove;

    if (nw == need) {
        if (tid < 64) wsel[tid] = (tid < nw) ? 1 : 0;
    } else {
        const float* xr = x + (size_t)b * KD;
        for (int w = 0; w < nw; w++) {
            const int s = wix[w];
            double part = 0.0;
            if (Wt) {
                const ushort* wr = Wt + (size_t)s * (2 * KD);
                for (int kk = tid; kk < KD; kk += 256) {
                    double wvd = (double)__half2float(__ushort_as_half(wr[kk]))
                               + (double)__half2float(__ushort_as_half(wr[kk + KD])) * (1.0 / 2048.0);
                    part += (double)xr[kk] * wvd;
                }
            } else {
                for (int kk = tid; kk < KD; kk += 256)
                    part += (double)xr[kk] * (double)W[(size_t)kk * DSAE + s];
            }
            dred[tid] = part; __syncthreads();
            for (int st = 128; st > 0; st >>= 1) { if (tid < st) dred[tid] += dred[tid + st]; __syncthreads(); }
            if (tid == 0) wdv[w] = dred[0];
            __syncthreads();
        }
        if (tid < 64) {
            unsigned char sel = 0;
            if (tid < nw) {
                int rank = 0;
                double mv = wdv[tid]; int mi = wix[tid];
                for (int w2 = 0; w2 < nw; w2++)
                    if (wdv[w2] > mv || (wdv[w2] == mv && wix[w2] < mi)) rank++;
                sel = (rank < need) ? 1 : 0;
            }
            wsel[tid] = sel;
        }
    }
    __syncthreads();

    for (int p = 0; p < DSAE / 256; p++) flag[tid + p * 256] = 0;
    __syncthreads();
    for (int p = 0; p < DSAE / 256; p++) {
        int i = tid + p * 256;
        if (vals[i] > v32 + mgn) flag[i] = 1;
    }
    if (tid < nw && wsel[tid]) flag[wix[tid]] = 1;
    __syncthreads();

    for (int p = 0; p < DSAE / 256; p++) {
        int i = tid + p * 256;
        float v = vals[i];
        float zv = 0.f;
        if (flag[i]) {
            zv = v > 0.f ? v : 0.f;
            int slot = atomicAdd(&outc, 1);
            if (slot < TOPK) { widx_g[b * TOPK + slot] = i; wval_g[b * TOPK + slot] = zv; }
        }
        zrow[i] = zv;
    }
}

// ---------------------------------------------------------------- K3: sparse decode + fused loss (384 threads)
__global__ __launch_bounds__(384) void decode_loss(const int* __restrict__ widx_g,
                                                   const float* __restrict__ wval_g,
                                                   const float* __restrict__ Wdec,
                                                   const float* __restrict__ bdec,
                                                   const float* __restrict__ x,
                                                   float* __restrict__ xhat,
                                                   double* __restrict__ acc)
{
    const int b = blockIdx.x, tid = threadIdx.x;
    __shared__ int sidx[TOPK]; __shared__ float sval[TOPK];
    __shared__ double dred[384];
    if (tid < TOPK) { sidx[tid] = widx_g[b * TOPK + tid]; sval[tid] = wval_g[b * TOPK + tid]; }
    __syncthreads();

    float4 o[2];
    #pragma unroll
    for (int c = 0; c < 2; c++) o[c] = ((const float4*)bdec)[tid + c * 384];

    float4 wn[2];
    {
        const float4* wr = (const float4*)(Wdec + (size_t)sidx[0] * KD);
        #pragma unroll
        for (int c = 0; c < 2; c++) wn[c] = wr[tid + c * 384];
    }
    for (int j = 0; j < TOPK; j++) {
        const float v = sval[j];
        float4 w[2];
        #pragma unroll
        for (int c = 0; c < 2; c++) w[c] = wn[c];
        if (j + 1 < TOPK) {
            const float4* wr = (const float4*)(Wdec + (size_t)sidx[j + 1] * KD);
            #pragma unroll
            for (int c = 0; c < 2; c++) wn[c] = wr[tid + c * 384];
        }
        #pragma unroll
        for (int c = 0; c < 2; c++) {
            o[c].x = fmaf(v, w[c].x, o[c].x);
            o[c].y = fmaf(v, w[c].y, o[c].y);
            o[c].z = fmaf(v, w[c].z, o[c].z);
            o[c].w = fmaf(v, w[c].w, o[c].w);
        }
    }

    double ls = 0.0;
    const float4* xr = (const float4*)(x + (size_t)b * KD);
    float* xo = xhat + (size_t)b * KD;     // offset 4 mod 16 -> scalar stores
    #pragma unroll
    for (int c = 0; c < 2; c++) {
        float4 xv = xr[tid + c * 384];
        float4 ov = o[c];
        float d0 = ov.x - xv.x, d1 = ov.y - xv.y, d2 = ov.z - xv.z, d3 = ov.w - xv.w;
        ls += (double)d0 * (double)d0 + (double)d1 * (double)d1
            + (double)d2 * (double)d2 + (double)d3 * (double)d3;
        const int e = (tid + c * 384) * 4;
        xo[e] = ov.x; xo[e + 1] = ov.y; xo[e + 2] = ov.z; xo[e + 3] = ov.w;
    }
    dred[tid] = ls; __syncthreads();
    if (tid < 128) dred[tid] += dred[tid + 256];
    __syncthreads();
    for (int s = 128; s > 0; s >>= 1) { if (tid < s) dred[tid] += dred[tid + s]; __syncthreads(); }
    if (tid == 0) atomicAdd(acc, dred[0]);
}

// ---------------------------------------------------------------- K4: finalize
__global__ void finalize(const double* __restrict__ acc, float* __restrict__ out)
{
    if (threadIdx.x == 0) out[0] = (float)(*acc / (double)(B_ * T_));
}

// ----------------------------------------------------------------
extern "C" void kernel_launch(void* const* d_in, const int* in_sizes, int n_in,
                              void* d_out, int out_size, void* d_ws, size_t ws_size,
                              hipStream_t stream)
{
    (void)in_sizes; (void)n_in; (void)out_size;
    const float* x    = (const float*)d_in[0];
    const float* Wenc = (const float*)d_in[1];
    const float* Wdec = (const float*)d_in[2];
    const float* benc = (const float*)d_in[3];
    const float* bdec = (const float*)d_in[4];

    float*  out    = (float*)d_out;
    double* acc    = (double*)d_ws;
    int*    widx_g = (int*)((char*)d_ws + 16);
    float*  wval_g = (float*)((char*)d_ws + 16 + (size_t)B_ * TOPK * 4);

    // tiered ws layout
    const size_t XC_OFF    = (size_t)1 << 20;                          // Xh  : 6.3 MB
    const size_t PRE_OFF   = (size_t)8 << 20;                          // pre : 32 MB (FULL tier)
    const size_t WT_OFF_F  = PRE_OFF + (size_t)B_ * DSAE * 4;          // 41,943,040
    const size_t NEED_FULL = WT_OFF_F + (size_t)DSAE * (2 * KD) * 2;   // ~136 MiB
    const size_t WT_OFF_M  = (size_t)8 << 20;
    const size_t NEED_MID  = WT_OFF_M + (size_t)DSAE * (2 * KD) * 2;   // ~104 MiB (round-3 layout)
    const int tier = (ws_size >= NEED_FULL) ? 2 : (ws_size >= NEED_MID ? 1 : 0);

    float* zreg = out + Z_OFF;     // z output region (4B-aligned)
    float* xhat = out + XHAT_OFF;

    if (tier >= 1) {
        ushort* Xh = (ushort*)((char*)d_ws + XC_OFF);
        ushort* Wt = (ushort*)((char*)d_ws + (tier == 2 ? WT_OFF_F : WT_OFF_M));
        float*  pre = (tier == 2) ? (float*)((char*)d_ws + PRE_OFF) : zreg;

        hipLaunchKernelGGL(convert_x,   dim3(3, B_),            dim3(256), 0, stream, x, Xh, acc);
        hipLaunchKernelGGL(convert_wT,  dim3(DSAE/32, KD/64),   dim3(256), 0, stream, Wenc, Wt);
        hipLaunchKernelGGL(encode_gemm, dim3(DSAE/128, B_/128), dim3(256), 0, stream, Xh, Wt, benc, pre);
        if (tier == 2)
            hipLaunchKernelGGL(select_topk_fast, dim3(B_), dim3(256), 0, stream,
                               pre, zreg, x, Wt, widx_g, wval_g, 1.25e-2f);
        else
            hipLaunchKernelGGL(select_topk, dim3(B_), dim3(256), 0, stream,
                               zreg, x, Wenc, Wt, widx_g, wval_g, 1.25e-2f);
    } else {
        hipLaunchKernelGGL(zero_acc,    dim3(1),                dim3(1),   0, stream, acc);
        hipLaunchKernelGGL(encode_mfma, dim3(DSAE/128, B_/128), dim3(256), 0, stream, x, Wenc, benc, zreg);
        hipLaunchKernelGGL(select_topk, dim3(B_), dim3(256), 0, stream,
                           zreg, x, Wenc, (const ushort*)nullptr, widx_g, wval_g, 2e-3f);
    }

    hipLaunchKernelGGL(decode_loss, dim3(B_), dim3(384), 0, stream, widx_g, wval_g, Wdec, bdec, x, xhat, acc);
    hipLaunchKernelGGL(finalize,    dim3(1),  dim3(1),   0, stream, acc, out);
}